// Round 11
// baseline (299.332 us; speedup 1.0000x reference)
//
#include <hip/hip_runtime.h>

#define N_NODES 50000
#define N_EDGES 10000
#define NNZ     800000
#define C       256
#define SLOPE   0.01f
#define KTOT    50176   // node count padded to 512*98
#define KCHUNK  512     // 8 * 64
#define NZB     98      // KTOT / KCHUNK
#define MPAD    10048   // edge count padded to multiple of 64
#define NHALF   25000   // node-id half boundary (edge-side partitions)

#define NB      250     // coarse buckets per side
#define EB_E    40      // edges per bucket   (250*40  = 10000)
#define EB_N    200     // nodes per bucket   (250*200 = 50000)
#define CHUNK   3125    // NNZ / 256 blocks
#define CAP     6000    // LDS item capacity in bucket_sort (mean 3200, sd ~57)
#define MP_E    288     // per-bucket pad slack, edge side (40 rows * 7 + align 8)
#define MP_N    1408    // per-bucket pad slack, node side (200 rows * 7 + align 8)

#define EAGG_G  314     // edge-agg blocks per partition (314*32 = 10048 = MPAD), 8 parts
#define NAGG_G  1568    // node-agg blocks per slice (1568*32 = 50176 = KTOT), 4 slices

// ---- workspace layout (bytes) ----
#define OFF_CC_E    0          // 250*4 coarse counts (edge)
#define OFF_CC_N    1024       // 250*4 coarse counts (node)
#define OFF_CUR_E   2048       // 250*4 scatter cursors
#define OFF_CUR_N   3072       // 250*4
#define OFF_DEG_E   4096       // 10048*4 row degrees (edge), pad rows ZERO
#define OFF_DEG_N   45056      // 50176*4 row degrees (node), pad rows ZERO
#define ZERO_BYTES  245760     // zero region: counters + deg arrays
#define OFF_CB_E    266240     // 251*4 coarse bases (edge)
#define OFF_CB_N    267264     // 251*4 coarse bases (node)
#define OFF_RS_N    268288     // 50001*4 PADDED row starts (written by bucket_sort)
#define OFF_RS_E    468480     // 10001*4 PADDED row starts (written by bucket_sort)
#define OFF_BUF_E   508672     // 800000*4 bucketed items (edge side)
#define OFF_BUF_N   3708672    // 800000*4 bucketed items (node side)
#define OFF_CSR_E   6908672    // <=872008*2 ushort node ids, rows 8-padded w/ sentinel
#define OFF_CSR_N   10108672   // <=1152000*2 ushort edge ids, rows 8-padded w/ sentinel
#define OFF_EMBH    13308672   // SLICE-MAJOR [4][50001][64ch] bf16 (node 50000 zero)
#define OFF_YT      13308672   // 256*50176*2 bf16 — ALIASES embh (embh dead before
                               // node_aggregate writes yT); ends 38,998,784
#define OFF_E2      44144640   // SLICE-MAJOR [4][10048][64ch] bf16; rows >=10000 ZERO
#define OFF_CWH     49289216   // 256*256*2 bf16 conv_w
#define OFF_PART    49420288   // 98*10*4096*4 gram partials -> end 65,476,608
#define OFF_EACCP   OFF_PART   // ALIASES part: [2][10048][256] bf16 edge partial sums
                               // (10.3MB < 16MB; dead before gram_mfma writes part)

typedef __attribute__((ext_vector_type(8))) short short8;
typedef __attribute__((ext_vector_type(4))) float floatx4;

static __device__ __forceinline__ unsigned short f2bf(float f) {
    unsigned int u = __float_as_uint(f);
    u = (u + 0x7fffu + ((u >> 16) & 1u)) >> 16;   // RNE
    return (unsigned short)u;
}

// unpack uint4 (8 bf16) and accumulate into a[0..7]
static __device__ __forceinline__ void acc_bf8(const uint4 d, float* a) {
    a[0] += __uint_as_float(d.x << 16);
    a[1] += __uint_as_float(d.x & 0xffff0000u);
    a[2] += __uint_as_float(d.y << 16);
    a[3] += __uint_as_float(d.y & 0xffff0000u);
    a[4] += __uint_as_float(d.z << 16);
    a[5] += __uint_as_float(d.z & 0xffff0000u);
    a[6] += __uint_as_float(d.w << 16);
    a[7] += __uint_as_float(d.w & 0xffff0000u);
}

// extract 8 ushort indices from one uint4 (16B of csr)
static __device__ __forceinline__ void idx8(const uint4 pk, int* ix) {
    ix[0] = (int)(pk.x & 0xffffu); ix[1] = (int)(pk.x >> 16);
    ix[2] = (int)(pk.y & 0xffffu); ix[3] = (int)(pk.y >> 16);
    ix[4] = (int)(pk.z & 0xffffu); ix[5] = (int)(pk.z >> 16);
    ix[6] = (int)(pk.w & 0xffffu); ix[7] = (int)(pk.w >> 16);
}

// bf16 pairwise add of two packed-bf16 words / uint4s (via f32)
static __device__ __forceinline__ unsigned bfadd2(unsigned x, unsigned y) {
    float lx = __uint_as_float(x << 16), hx = __uint_as_float(x & 0xffff0000u);
    float ly = __uint_as_float(y << 16), hy = __uint_as_float(y & 0xffff0000u);
    return (unsigned)f2bf(lx + ly) | ((unsigned)f2bf(hx + hy) << 16);
}
static __device__ __forceinline__ uint4 bfadd8(uint4 x, uint4 y) {
    x.x = bfadd2(x.x, y.x); x.y = bfadd2(x.y, y.y);
    x.z = bfadd2(x.z, y.z); x.w = bfadd2(x.w, y.w);
    return x;
}

__global__ __launch_bounds__(256) void zero_kernel(float4* __restrict__ p, int n4) {
    int i = blockIdx.x * 256 + threadIdx.x;
    if (i < n4) p[i] = make_float4(0.f, 0.f, 0.f, 0.f);
}

// FUSED prep: blocks [0,6251) cast emb->bf16 SLICE-MAJOR [4][50001][64ch],
// [6251,6283) cast conv_w->bf16, [6283,6539) coarse histogram.
#define PREP_EMB_BLOCKS 6251
#define PREP_CW_BLOCKS  32
__global__ __launch_bounds__(256) void prep_kernel(const float4* __restrict__ emb4,
                                                   uint4* __restrict__ embh4,
                                                   const float4* __restrict__ cw4,
                                                   uint4* __restrict__ cwh4,
                                                   const int* __restrict__ node_idx,
                                                   const int* __restrict__ edge_idx,
                                                   int* __restrict__ cc_e,
                                                   int* __restrict__ cc_n) {
    __shared__ int he[NB], hn[NB];
    int b = blockIdx.x, tid = threadIdx.x;
    if (b < PREP_EMB_BLOCKS) {
        int i = b * 256 + tid;
        if (i >= 1600032) return;
        uint4 o = {0u, 0u, 0u, 0u};
        if (i < 1600000) {
            float4 f0 = emb4[2 * i], f1 = emb4[2 * i + 1];
            o.x = f2bf(f0.x) | ((unsigned)f2bf(f0.y) << 16);
            o.y = f2bf(f0.z) | ((unsigned)f2bf(f0.w) << 16);
            o.z = f2bf(f1.x) | ((unsigned)f2bf(f1.y) << 16);
            o.w = f2bf(f1.z) | ((unsigned)f2bf(f1.w) << 16);
        }
        // slice-major 64ch: node = i>>5, chunk c = i&31 (8 ch each),
        // slice = c>>3 (4 slices of 8 uint4), pos = c&7
        int node = i >> 5, c = i & 31;
        embh4[((size_t)(c >> 3) * 50001 + node) * 8 + (c & 7)] = o;
    } else if (b < PREP_EMB_BLOCKS + PREP_CW_BLOCKS) {
        int i = (b - PREP_EMB_BLOCKS) * 256 + tid;   // < 8192
        float4 f0 = cw4[2 * i], f1 = cw4[2 * i + 1];
        uint4 o;
        o.x = f2bf(f0.x) | ((unsigned)f2bf(f0.y) << 16);
        o.y = f2bf(f0.z) | ((unsigned)f2bf(f0.w) << 16);
        o.z = f2bf(f1.x) | ((unsigned)f2bf(f1.y) << 16);
        o.w = f2bf(f1.z) | ((unsigned)f2bf(f1.w) << 16);
        cwh4[i] = o;
    } else {
        int base = (b - PREP_EMB_BLOCKS - PREP_CW_BLOCKS) * CHUNK;
        for (int i = tid; i < NB; i += 256) { he[i] = 0; hn[i] = 0; }
        __syncthreads();
        for (int i = tid; i < CHUNK; i += 256) {
            atomicAdd(&he[edge_idx[base + i] / EB_E], 1);
            atomicAdd(&hn[node_idx[base + i] / EB_N], 1);
        }
        __syncthreads();
        for (int k = tid; k < NB; k += 256) {
            if (he[k]) atomicAdd(&cc_e[k], he[k]);
            if (hn[k]) atomicAdd(&cc_n[k], hn[k]);
        }
    }
}

// single-block exclusive scan of both coarse-count arrays -> coarse bases
__global__ __launch_bounds__(256) void coarse_scan_kernel(const int* __restrict__ cc_e,
                                                          const int* __restrict__ cc_n,
                                                          int* __restrict__ cb_e,
                                                          int* __restrict__ cb_n) {
    __shared__ int tmp[256];
    int tid = threadIdx.x;
    int v = (tid < NB) ? cc_e[tid] : 0;
    tmp[tid] = v;
    __syncthreads();
    for (int off = 1; off < 256; off <<= 1) {
        int t = (tid >= off) ? tmp[tid - off] : 0;
        __syncthreads();
        tmp[tid] += t;
        __syncthreads();
    }
    if (tid < NB) cb_e[tid + 1] = tmp[tid];
    if (tid == 0) cb_e[0] = 0;
    __syncthreads();
    v = (tid < NB) ? cc_n[tid] : 0;
    tmp[tid] = v;
    __syncthreads();
    for (int off = 1; off < 256; off <<= 1) {
        int t = (tid >= off) ? tmp[tid - off] : 0;
        __syncthreads();
        tmp[tid] += t;
        __syncthreads();
    }
    if (tid < NB) cb_n[tid + 1] = tmp[tid];
    if (tid == 0) cb_n[0] = 0;
}

// pass 1: scatter into coarse buckets. Single LDS-hist pass: the pass-1
// atomicAdd return value IS the local offset — carried in registers.
__global__ __launch_bounds__(256) void bucket_scatter_kernel(const int* __restrict__ node_idx,
                                                             const int* __restrict__ edge_idx,
                                                             const int* __restrict__ cb_e,
                                                             const int* __restrict__ cb_n,
                                                             int* __restrict__ cur_e,
                                                             int* __restrict__ cur_n,
                                                             int* __restrict__ buf_e,
                                                             int* __restrict__ buf_n) {
    __shared__ int he[NB], hn[NB], be[NB], bn[NB];
    int tid = threadIdx.x;
    int base = blockIdx.x * CHUNK;
    for (int i = tid; i < NB; i += 256) { he[i] = 0; hn[i] = 0; }
    __syncthreads();
    int pe[13], pn[13];   // (bucket<<12) | local_offset ; offset < 3125 < 4096
    #pragma unroll
    for (int k = 0; k < 13; k++) {
        int i = tid + k * 256;
        if (i < CHUNK) {
            int e = edge_idx[base + i], v = node_idx[base + i];
            int ke = e / EB_E, kn = v / EB_N;
            pe[k] = (ke << 12) | atomicAdd(&he[ke], 1);
            pn[k] = (kn << 12) | atomicAdd(&hn[kn], 1);
        }
    }
    __syncthreads();
    for (int k = tid; k < NB; k += 256) {
        int c = he[k];
        be[k] = cb_e[k] + (c ? atomicAdd(&cur_e[k], c) : 0);
        int cn = hn[k];
        bn[k] = cb_n[k] + (cn ? atomicAdd(&cur_n[k], cn) : 0);
    }
    __syncthreads();
    #pragma unroll
    for (int k = 0; k < 13; k++) {
        int i = tid + k * 256;
        if (i < CHUNK) {
            int e = edge_idx[base + i], v = node_idx[base + i];
            int ke = pe[k] >> 12, oe = pe[k] & 4095;
            buf_e[be[ke] + oe] = (v << 6) | (e - ke * EB_E);
            int kn = pn[k] >> 12, on = pn[k] & 4095;
            buf_n[bn[kn] + on] = (e << 8) | (v - kn * EB_N);
        }
    }
}

// pass 2: per-bucket LDS counting sort -> PADDED CSR (rows 8-aligned, padded
// to multiple of 8 with zero-sentinel ids) + padded row starts rs + deg array.
__global__ __launch_bounds__(256) void bucket_sort_kernel(const int* __restrict__ buf_e,
                                                          const int* __restrict__ buf_n,
                                                          const int* __restrict__ cb_e,
                                                          const int* __restrict__ cb_n,
                                                          unsigned short* __restrict__ csr_e,
                                                          unsigned short* __restrict__ csr_n,
                                                          int* __restrict__ rs_e,
                                                          int* __restrict__ rs_n,
                                                          int* __restrict__ deg_e,
                                                          int* __restrict__ deg_n) {
    __shared__ int A[CAP];
    __shared__ int h[EB_N], bs[EB_N], cs[EB_N];
    int tid = threadIdx.x;
    bool edgeSide = blockIdx.x < NB;
    int k = edgeSide ? blockIdx.x : blockIdx.x - NB;
    int eb = edgeSide ? EB_E : EB_N;
    int shift = edgeSide ? 6 : 8;
    int mask = (1 << shift) - 1;
    int mp = edgeSide ? MP_E : MP_N;
    int sent = edgeSide ? N_NODES : N_EDGES;
    const int* cb  = edgeSide ? cb_e : cb_n;
    const int* buf = edgeSide ? buf_e : buf_n;
    unsigned short* csr = edgeSide ? csr_e : csr_n;
    int* rs  = edgeSide ? rs_e : rs_n;
    int* deg = edgeSide ? deg_e : deg_n;
    int base = cb[k];                               // exact base (buf reads)
    int base_pad = (base + k * mp + 7) & ~7;        // 8-aligned padded base (csr writes)
    int cnt = cb[k + 1] - base;
    for (int i = tid; i < eb; i += 256) h[i] = 0;
    __syncthreads();
    for (int i = tid; i < cnt; i += 256) {
        int it = buf[base + i];
        if (i < CAP) A[i] = it;
        atomicAdd(&h[it & mask], 1);
    }
    __syncthreads();
    if (tid == 0) {
        int s = 0;
        for (int j = 0; j < eb; j++) { bs[j] = s; s += (h[j] + 7) & ~7; }
    }
    __syncthreads();
    for (int j = tid; j < eb; j += 256) {
        rs[k * eb + j] = base_pad + bs[j];
        deg[k * eb + j] = h[j];
        cs[j] = h[j];
        h[j] = 0;
    }
    if (tid == 0 && k == NB - 1) rs[edgeSide ? N_EDGES : N_NODES] = NNZ;
    __syncthreads();
    // fill pad slots with sentinel (disjoint from scatter slots)
    for (int j = tid; j < eb; j += 256) {
        int c0 = cs[j], e0 = (c0 + 7) & ~7;
        for (int x = c0; x < e0; x++) csr[base_pad + bs[j] + x] = (unsigned short)sent;
    }
    for (int i = tid; i < cnt; i += 256) {
        int it = (i < CAP) ? A[i] : buf[base + i];
        int loc = it & mask;
        int off = bs[loc] + atomicAdd(&h[loc], 1);
        csr[base_pad + off] = (unsigned short)(it >> shift);
    }
}

// Edge aggregation, 8 partitions = 4 ch-slices x 2 node-halves (3.2MB each,
// one per XCD). Each 8-lane group owns an edge; lanes cover one contiguous
// 128B row -> HALF the L2 requests vs 64B slices. Broadcast csr chunk; the
// in-half test is uniform per group (exec-mask skip, sentinel 50000 excluded
// by both halves). NO cross-lane reduction. Writes bf16 PARTIAL sums
// e_accP[half][MPAD][256] (combined in edge_gemm staging).
__global__ __launch_bounds__(256) void edge_aggregate_kernel(const uint4* __restrict__ embh4,
                                                             const unsigned short* __restrict__ csr_e,
                                                             const int* __restrict__ rs_e,
                                                             const int* __restrict__ deg_e,
                                                             unsigned short* __restrict__ e_accp) {
    int sid = blockIdx.x & 7, g = blockIdx.x >> 3;  // g in [0, 314)
    int cslice = sid & 3, half = sid >> 2;
    int lo = half * NHALF, hi = lo + NHALF;
    const uint4* __restrict__ csr4 = (const uint4*)csr_e;
    int tid = threadIdx.x;
    int group = tid >> 3, l8 = tid & 7;
    const uint4* __restrict__ tbl = embh4 + (size_t)cslice * 50001 * 8 + l8;
    int e = g * 32 + group;                         // < MPAD (314*32 = 10048)
    int s = rs_e[min(e, N_EDGES)];
    int dg = deg_e[e];                              // pad rows: 0 -> loop skipped
    int c0 = s >> 3, nc = (dg + 7) >> 3;
    float a[8] = {0.f, 0.f, 0.f, 0.f, 0.f, 0.f, 0.f, 0.f};
    for (int c = c0; c < c0 + nc; c++) {
        uint4 pk = csr4[c];                         // broadcast across the 8 lanes
        int ix[8];
        idx8(pk, ix);
        #pragma unroll
        for (int j = 0; j < 8; j++) {
            int v = ix[j];
            if (v >= lo && v < hi)                  // uniform within 8-lane group
                acc_bf8(tbl[(size_t)v * 8], a);
        }
    }
    uint4 o;
    o.x = f2bf(a[0]) | ((unsigned)f2bf(a[1]) << 16);
    o.y = f2bf(a[2]) | ((unsigned)f2bf(a[3]) << 16);
    o.z = f2bf(a[4]) | ((unsigned)f2bf(a[5]) << 16);
    o.w = f2bf(a[6]) | ((unsigned)f2bf(a[7]) << 16);
    *(uint4*)(e_accp + ((size_t)half * MPAD + e) * C + cslice * 64 + l8 * 8) = o;
}

// e2[m][n] = Binv[m] * sum_k (e_accP0+e_accP1)[m][k] * conv_w[n][k] via MFMA;
// grid (157,4); output SLICE-MAJOR [4][MPAD][64ch]; pad rows ZERO.
__global__ __launch_bounds__(256) void edge_gemm_mfma_kernel(const unsigned short* __restrict__ e_accp,
                                                             const unsigned short* __restrict__ cwh,
                                                             const int* __restrict__ deg_e,
                                                             unsigned short* __restrict__ e2h) {
    __shared__ __align__(16) unsigned short As[64 * 72];
    __shared__ __align__(16) unsigned short Bs[64 * 72];
    int i0 = blockIdx.x * 64, j0 = blockIdx.y * 64;
    int tid = threadIdx.x;
    int w = tid >> 6, lane = tid & 63;
    int col = lane & 15, quad = lane >> 4;
    floatx4 acc[4] = {};
    for (int step = 0; step < 4; step++) {
        int kb = step * 64;
        __syncthreads();
        #pragma unroll
        for (int l = 0; l < 2; l++) {
            int slot = tid + l * 256;
            int row = slot >> 3, grp = slot & 7;
            uint4 d0 = *(const uint4*)(e_accp + (size_t)(i0 + row) * C + kb + grp * 8);
            uint4 d1 = *(const uint4*)(e_accp + ((size_t)MPAD + i0 + row) * C + kb + grp * 8);
            *(uint4*)(&As[row * 72 + grp * 8]) = bfadd8(d0, d1);   // combine halves
            uint4 db = *(const uint4*)(cwh + (size_t)(j0 + row) * C + kb + grp * 8);
            *(uint4*)(&Bs[row * 72 + grp * 8]) = db;
        }
        __syncthreads();
        #pragma unroll
        for (int sub = 0; sub < 2; sub++) {
            short8 a = *(const short8*)(&As[(w * 16 + col) * 72 + sub * 32 + quad * 8]);
            #pragma unroll
            for (int jt = 0; jt < 4; jt++) {
                short8 b = *(const short8*)(&Bs[(jt * 16 + col) * 72 + sub * 32 + quad * 8]);
                acc[jt] = __builtin_amdgcn_mfma_f32_16x16x32_bf16(a, b, acc[jt], 0, 0, 0);
            }
        }
    }
    #pragma unroll
    for (int r = 0; r < 4; r++) {
        int m = i0 + w * 16 + quad * 4 + r;          // < MPAD always
        int dg = deg_e[m];                           // pad rows: 0
        float binv = (dg > 0) ? 1.0f / (float)dg : 0.0f;
        #pragma unroll
        for (int jt = 0; jt < 4; jt++) {
            int ch = j0 + jt * 16 + col;
            e2h[(size_t)((ch >> 6) * MPAD + m) * 64 + (ch & 63)] = f2bf(acc[jt][r] * binv);
        }
    }
}

// XCD-sliced node aggregation, 64-CHANNEL slices (4 slices, table 1.28MB,
// L2-resident; sid = blockIdx&3): each 8-LANE group owns a node; 8 lanes
// cover one contiguous 128B row -> one L2 request per incidence-slice.
// csr chunk load is wave-broadcast. Unconditional unpack (rows 8-padded).
// Fused Dinv/bias/lrelu; LDS transpose; 16B yT stores.
__global__ __launch_bounds__(256) void node_aggregate_t_kernel(const uint4* __restrict__ e2h4,
                                                               const unsigned short* __restrict__ csr_n,
                                                               const int* __restrict__ rs_n,
                                                               const int* __restrict__ deg_n,
                                                               const float* __restrict__ conv_b,
                                                               unsigned short* __restrict__ yT) {
    __shared__ unsigned short T[64][33];   // [slice-ch][node-local], stride 33
    int sid = blockIdx.x & 3, g = blockIdx.x >> 2;
    const uint4* __restrict__ csr4 = (const uint4*)csr_n;
    int tid = threadIdx.x;
    int group = tid >> 3, l8 = tid & 7;
    const uint4* __restrict__ tbl = e2h4 + (size_t)sid * MPAD * 8 + l8;
    int n = g * 32 + group;                         // < KTOT (1568*32 = 50176)
    int s = rs_n[min(n, N_NODES)];
    int dg = deg_n[n];
    int c0 = s >> 3, nc = (dg + 7) >> 3;
    float4 b0 = ((const float4*)conv_b)[sid * 16 + l8 * 2];
    float4 b1 = ((const float4*)conv_b)[sid * 16 + l8 * 2 + 1];
    float a[8] = {0.f, 0.f, 0.f, 0.f, 0.f, 0.f, 0.f, 0.f};
    for (int c = c0; c < c0 + nc; c++) {
        uint4 pk = csr4[c];                         // broadcast across the 8 lanes
        int ix[8];
        idx8(pk, ix);
        #pragma unroll
        for (int j = 0; j < 8; j++) acc_bf8(tbl[(size_t)ix[j] * 8], a);
    }
    float dinv = (dg > 0) ? 1.0f / (float)dg : 0.0f;
    float bb[8] = {b0.x, b0.y, b0.z, b0.w, b1.x, b1.y, b1.z, b1.w};
    #pragma unroll
    for (int jj = 0; jj < 8; jj++) {
        float r = a[jj] * dinv + bb[jj];
        r = (r > 0.f) ? r : SLOPE * r;
        if (n >= N_NODES) r = 0.f;                 // zero-pad rows for gram
        T[l8 * 8 + jj][group] = f2bf(r);
    }
    __syncthreads();
    int rr = tid >> 2, cc = tid & 3;               // 64 rows x 4 packers
    uint4 o;
    o.x = T[rr][cc * 8 + 0] | ((unsigned)T[rr][cc * 8 + 1] << 16);
    o.y = T[rr][cc * 8 + 2] | ((unsigned)T[rr][cc * 8 + 3] << 16);
    o.z = T[rr][cc * 8 + 4] | ((unsigned)T[rr][cc * 8 + 5] << 16);
    o.w = T[rr][cc * 8 + 6] | ((unsigned)T[rr][cc * 8 + 7] << 16);
    *(uint4*)(yT + (size_t)(sid * 64 + rr) * KTOT + g * 32 + cc * 8) = o;
}

// Gram partials via MFMA, symmetry-aware (10 upper-tri tile pairs), NO atomics.
__global__ __launch_bounds__(256) void gram_mfma_kernel(const unsigned short* __restrict__ yT,
                                                        float* __restrict__ part) {
    static const int PI[10] = {0, 0, 0, 0, 1, 1, 1, 2, 2, 3};
    static const int PJ[10] = {0, 1, 2, 3, 1, 2, 3, 2, 3, 3};
    __shared__ __align__(16) unsigned short As[64 * 72];  // [col][k], stride 72
    __shared__ __align__(16) unsigned short Bs[64 * 72];
    int i0 = PI[blockIdx.x] * 64, j0 = PJ[blockIdx.x] * 64;
    bool diag = (i0 == j0);
    int kb0 = blockIdx.y * KCHUNK;
    int tid = threadIdx.x;
    int w = tid >> 6, lane = tid & 63;
    int col = lane & 15, quad = lane >> 4;
    floatx4 acc[4] = {};
    for (int step = 0; step < KCHUNK / 64; step++) {
        int kb = kb0 + step * 64;
        __syncthreads();
        #pragma unroll
        for (int l = 0; l < 2; l++) {
            int slot = tid + l * 256;
            int row = slot >> 3, grp = slot & 7;
            uint4 da = *(const uint4*)(yT + (size_t)(i0 + row) * KTOT + kb + grp * 8);
            *(uint4*)(&As[row * 72 + grp * 8]) = da;
            if (!diag) {
                uint4 db = *(const uint4*)(yT + (size_t)(j0 + row) * KTOT + kb + grp * 8);
                *(uint4*)(&Bs[row * 72 + grp * 8]) = db;
            }
        }
        __syncthreads();
        const unsigned short* Bb = diag ? As : Bs;
        #pragma unroll
        for (int sub = 0; sub < 2; sub++) {
            short8 a = *(const short8*)(&As[(w * 16 + col) * 72 + sub * 32 + quad * 8]);
            #pragma unroll
            for (int jt = 0; jt < 4; jt++) {
                short8 b = *(const short8*)(&Bb[(jt * 16 + col) * 72 + sub * 32 + quad * 8]);
                acc[jt] = __builtin_amdgcn_mfma_f32_16x16x32_bf16(a, b, acc[jt], 0, 0, 0);
            }
        }
    }
    float* slab = part + ((size_t)blockIdx.y * 10 + blockIdx.x) * 4096;
    #pragma unroll
    for (int jt = 0; jt < 4; jt++)
        #pragma unroll
        for (int r = 0; r < 4; r++)
            slab[(w * 16 + quad * 4 + r) * 64 + jt * 16 + col] = acc[jt][r];
}

// FUSED: block i reduces g row i from the 98 partial slabs (with symmetric
// mirror) into LDS, then computes out row i = lrelu(g_row @ lin_w^T + lin_b).
__global__ __launch_bounds__(256) void greduce_out_kernel(const float* __restrict__ part,
                                                          const float* __restrict__ lin_w,
                                                          const float* __restrict__ lin_b,
                                                          float* __restrict__ out) {
    __shared__ float gs[C];
    int i = blockIdx.x, j = threadIdx.x;
    int a = i >> 6, b = j >> 6;
    int lo = min(a, b), hi = max(a, b);
    int t = lo * (7 - lo) / 2 + hi;          // pair index in PI/PJ order
    int li = (a <= b) ? (i & 63) : (j & 63);
    int lj = (a <= b) ? (j & 63) : (i & 63);
    const float* p = part + (size_t)t * 4096 + li * 64 + lj;
    float s = 0.f;
    for (int z = 0; z < NZB; z++) s += p[(size_t)z * 40960];
    gs[j] = s;
    __syncthreads();
    float acc = lin_b[j];
    const float* wrow = lin_w + (size_t)j * C;
    for (int k = 0; k < C; k++) acc += gs[k] * wrow[k];
    out[(size_t)i * C + j] = (acc > 0.f) ? acc : SLOPE * acc;
}

extern "C" void kernel_launch(void* const* d_in, const int* in_sizes, int n_in,
                              void* d_out, int out_size, void* d_ws, size_t ws_size,
                              hipStream_t stream) {
    const float* emb    = (const float*)d_in[0];
    const float* conv_w = (const float*)d_in[1];
    const float* conv_b = (const float*)d_in[2];
    const float* lin_w  = (const float*)d_in[3];
    const float* lin_b  = (const float*)d_in[4];
    const int*   eidx   = (const int*)d_in[5];
    const int* node_idx = eidx;        // edge_index[0]
    const int* edge_idx = eidx + NNZ;  // edge_index[1]

    char* ws = (char*)d_ws;
    int* cc_e  = (int*)(ws + OFF_CC_E);
    int* cc_n  = (int*)(ws + OFF_CC_N);
    int* cur_e = (int*)(ws + OFF_CUR_E);
    int* cur_n = (int*)(ws + OFF_CUR_N);
    int* deg_e = (int*)(ws + OFF_DEG_E);
    int* deg_n = (int*)(ws + OFF_DEG_N);
    int* cb_e  = (int*)(ws + OFF_CB_E);
    int* cb_n  = (int*)(ws + OFF_CB_N);
    int* rs_n  = (int*)(ws + OFF_RS_N);
    int* rs_e  = (int*)(ws + OFF_RS_E);
    int* buf_e = (int*)(ws + OFF_BUF_E);
    int* buf_n = (int*)(ws + OFF_BUF_N);
    unsigned short* csr_e = (unsigned short*)(ws + OFF_CSR_E);
    unsigned short* csr_n = (unsigned short*)(ws + OFF_CSR_N);
    uint4* embh4 = (uint4*)(ws + OFF_EMBH);
    unsigned short* e_accp = (unsigned short*)(ws + OFF_EACCP);
    unsigned short* e2h = (unsigned short*)(ws + OFF_E2);
    unsigned short* cwh = (unsigned short*)(ws + OFF_CWH);
    unsigned short* yT  = (unsigned short*)(ws + OFF_YT);
    float* part = (float*)(ws + OFF_PART);
    float* out = (float*)d_out;

    zero_kernel<<<ZERO_BYTES / 4096, 256, 0, stream>>>((float4*)ws, ZERO_BYTES / 16);

    prep_kernel<<<PREP_EMB_BLOCKS + PREP_CW_BLOCKS + 256, 256, 0, stream>>>(
        (const float4*)emb, embh4, (const float4*)conv_w, (uint4*)cwh,
        node_idx, edge_idx, cc_e, cc_n);

    coarse_scan_kernel<<<1, 256, 0, stream>>>(cc_e, cc_n, cb_e, cb_n);

    bucket_scatter_kernel<<<256, 256, 0, stream>>>(node_idx, edge_idx, cb_e, cb_n,
                                                   cur_e, cur_n, buf_e, buf_n);

    bucket_sort_kernel<<<2 * NB, 256, 0, stream>>>(buf_e, buf_n, cb_e, cb_n,
                                                   csr_e, csr_n, rs_e, rs_n,
                                                   deg_e, deg_n);

    edge_aggregate_kernel<<<8 * EAGG_G, 256, 0, stream>>>(embh4, csr_e, rs_e, deg_e, e_accp);

    edge_gemm_mfma_kernel<<<dim3(MPAD / 64, C / 64), 256, 0, stream>>>(e_accp, cwh, deg_e, e2h);

    node_aggregate_t_kernel<<<4 * NAGG_G, 256, 0, stream>>>((const uint4*)e2h, csr_n, rs_n,
                                                            deg_n, conv_b, yT);

    gram_mfma_kernel<<<dim3(10, NZB), 256, 0, stream>>>(yT, part);

    greduce_out_kernel<<<C, 256, 0, stream>>>(part, lin_w, lin_b, out);
}

// Round 12
// 258.708 us; speedup vs baseline: 1.1570x; 1.1570x over previous
//
#include <hip/hip_runtime.h>

#define N_NODES 50000
#define N_EDGES 10000
#define NNZ     800000
#define C       256
#define SLOPE   0.01f
#define KTOT    50176   // node count padded to 512*98
#define KCHUNK  512     // 8 * 64
#define NZB     98      // KTOT / KCHUNK
#define MPAD    10048   // edge count padded to multiple of 64
#define NHALF   25000   // node-id half boundary (edge-side partitions)

#define NB      250     // coarse buckets per side
#define EB_E    40      // edges per bucket   (250*40  = 10000)
#define EB_N    200     // nodes per bucket   (250*200 = 50000)
#define CHUNK   3125    // NNZ / 256 blocks
#define CAP     6000    // LDS item capacity in bucket_sort (mean 3200, sd ~57)
#define MP_E    576     // per-bucket pad slack, edge side (80 bins * 7 + align 8)
#define MP_N    1408    // per-bucket pad slack, node side (200 rows * 7 + align 8)

#define EAGG_G  314     // edge-agg blocks per partition (314*32 = 10048 = MPAD), 8 parts
#define NAGG_G  1568    // node-agg blocks per slice (1568*32 = 50176 = KTOT), 4 slices

// ---- workspace layout (bytes) ----
#define OFF_CC_E    0          // 250*4 coarse counts (edge)
#define OFF_CC_N    1024       // 250*4 coarse counts (node)
#define OFF_CUR_E   2048       // 250*4 scatter cursors
#define OFF_CUR_N   3072       // 250*4
#define ZERO_BYTES  4096       // zero region: counters only (deg pads written by sort)
#define OFF_DEG_E0  4096       // 10048*4 half-0 degrees -> 44288
#define OFF_DEG_E1  45056      // 10048*4 half-1 degrees -> 85248
#define OFF_DEG_N   86016      // 50176*4 node degrees -> 286720
#define OFF_CB_E    286720     // 251*4 coarse bases (edge)
#define OFF_CB_N    288768     // 251*4 coarse bases (node)
#define OFF_RS_N    290816     // 50001*4 PADDED row starts -> 490820
#define OFF_RS_E    491520     // 10001*4 PADDED row starts (half0 base) -> 531524
#define OFF_BUF_E   532480     // 800000*4 bucketed items (edge side)
#define OFF_BUF_N   3732480    // 800000*4 bucketed items (node side)
#define OFF_CSR_E   6932480    // <=944000*2 ushort node ids, per-HALF 8-padded
#define OFF_CSR_N   8820480    // <=1152000*2 ushort edge ids, rows 8-padded
#define OFF_EMBH    13308672   // SLICE-MAJOR [4][50001][64ch] bf16 (node 50000 zero)
#define OFF_YT      13308672   // 256*50176*2 bf16 — ALIASES embh (embh dead before
                               // node_aggregate writes yT); ends 38,998,784
#define OFF_E2      44144640   // SLICE-MAJOR [4][10048][64ch] bf16; rows >=10000 ZERO
#define OFF_CWH     49289216   // 256*256*2 bf16 conv_w
#define OFF_PART    49420288   // 98*10*4096*4 gram partials -> end 65,476,608
#define OFF_EACCP   OFF_PART   // ALIASES part: [2][10048][256] bf16 edge partial sums

typedef __attribute__((ext_vector_type(8))) short short8;
typedef __attribute__((ext_vector_type(4))) float floatx4;

static __device__ __forceinline__ unsigned short f2bf(float f) {
    unsigned int u = __float_as_uint(f);
    u = (u + 0x7fffu + ((u >> 16) & 1u)) >> 16;   // RNE
    return (unsigned short)u;
}

// unpack uint4 (8 bf16) and accumulate into a[0..7]
static __device__ __forceinline__ void acc_bf8(const uint4 d, float* a) {
    a[0] += __uint_as_float(d.x << 16);
    a[1] += __uint_as_float(d.x & 0xffff0000u);
    a[2] += __uint_as_float(d.y << 16);
    a[3] += __uint_as_float(d.y & 0xffff0000u);
    a[4] += __uint_as_float(d.z << 16);
    a[5] += __uint_as_float(d.z & 0xffff0000u);
    a[6] += __uint_as_float(d.w << 16);
    a[7] += __uint_as_float(d.w & 0xffff0000u);
}

// extract 8 ushort indices from one uint4 (16B of csr)
static __device__ __forceinline__ void idx8(const uint4 pk, int* ix) {
    ix[0] = (int)(pk.x & 0xffffu); ix[1] = (int)(pk.x >> 16);
    ix[2] = (int)(pk.y & 0xffffu); ix[3] = (int)(pk.y >> 16);
    ix[4] = (int)(pk.z & 0xffffu); ix[5] = (int)(pk.z >> 16);
    ix[6] = (int)(pk.w & 0xffffu); ix[7] = (int)(pk.w >> 16);
}

// bf16 pairwise add of two packed-bf16 words / uint4s (via f32)
static __device__ __forceinline__ unsigned bfadd2(unsigned x, unsigned y) {
    float lx = __uint_as_float(x << 16), hx = __uint_as_float(x & 0xffff0000u);
    float ly = __uint_as_float(y << 16), hy = __uint_as_float(y & 0xffff0000u);
    return (unsigned)f2bf(lx + ly) | ((unsigned)f2bf(hx + hy) << 16);
}
static __device__ __forceinline__ uint4 bfadd8(uint4 x, uint4 y) {
    x.x = bfadd2(x.x, y.x); x.y = bfadd2(x.y, y.y);
    x.z = bfadd2(x.z, y.z); x.w = bfadd2(x.w, y.w);
    return x;
}

__global__ __launch_bounds__(256) void zero_kernel(float4* __restrict__ p, int n4) {
    int i = blockIdx.x * 256 + threadIdx.x;
    if (i < n4) p[i] = make_float4(0.f, 0.f, 0.f, 0.f);
}

// FUSED prep: blocks [0,6251) cast emb->bf16 SLICE-MAJOR [4][50001][64ch],
// [6251,6283) cast conv_w->bf16, [6283,6539) coarse histogram.
#define PREP_EMB_BLOCKS 6251
#define PREP_CW_BLOCKS  32
__global__ __launch_bounds__(256) void prep_kernel(const float4* __restrict__ emb4,
                                                   uint4* __restrict__ embh4,
                                                   const float4* __restrict__ cw4,
                                                   uint4* __restrict__ cwh4,
                                                   const int* __restrict__ node_idx,
                                                   const int* __restrict__ edge_idx,
                                                   int* __restrict__ cc_e,
                                                   int* __restrict__ cc_n) {
    __shared__ int he[NB], hn[NB];
    int b = blockIdx.x, tid = threadIdx.x;
    if (b < PREP_EMB_BLOCKS) {
        int i = b * 256 + tid;
        if (i >= 1600032) return;
        uint4 o = {0u, 0u, 0u, 0u};
        if (i < 1600000) {
            float4 f0 = emb4[2 * i], f1 = emb4[2 * i + 1];
            o.x = f2bf(f0.x) | ((unsigned)f2bf(f0.y) << 16);
            o.y = f2bf(f0.z) | ((unsigned)f2bf(f0.w) << 16);
            o.z = f2bf(f1.x) | ((unsigned)f2bf(f1.y) << 16);
            o.w = f2bf(f1.z) | ((unsigned)f2bf(f1.w) << 16);
        }
        // slice-major 64ch: node = i>>5, chunk c = i&31 (8 ch each),
        // slice = c>>3 (4 slices of 8 uint4), pos = c&7
        int node = i >> 5, c = i & 31;
        embh4[((size_t)(c >> 3) * 50001 + node) * 8 + (c & 7)] = o;
    } else if (b < PREP_EMB_BLOCKS + PREP_CW_BLOCKS) {
        int i = (b - PREP_EMB_BLOCKS) * 256 + tid;   // < 8192
        float4 f0 = cw4[2 * i], f1 = cw4[2 * i + 1];
        uint4 o;
        o.x = f2bf(f0.x) | ((unsigned)f2bf(f0.y) << 16);
        o.y = f2bf(f0.z) | ((unsigned)f2bf(f0.w) << 16);
        o.z = f2bf(f1.x) | ((unsigned)f2bf(f1.y) << 16);
        o.w = f2bf(f1.z) | ((unsigned)f2bf(f1.w) << 16);
        cwh4[i] = o;
    } else {
        int base = (b - PREP_EMB_BLOCKS - PREP_CW_BLOCKS) * CHUNK;
        for (int i = tid; i < NB; i += 256) { he[i] = 0; hn[i] = 0; }
        __syncthreads();
        for (int i = tid; i < CHUNK; i += 256) {
            atomicAdd(&he[edge_idx[base + i] / EB_E], 1);
            atomicAdd(&hn[node_idx[base + i] / EB_N], 1);
        }
        __syncthreads();
        for (int k = tid; k < NB; k += 256) {
            if (he[k]) atomicAdd(&cc_e[k], he[k]);
            if (hn[k]) atomicAdd(&cc_n[k], hn[k]);
        }
    }
}

// single-block exclusive scan of both coarse-count arrays -> coarse bases
__global__ __launch_bounds__(256) void coarse_scan_kernel(const int* __restrict__ cc_e,
                                                          const int* __restrict__ cc_n,
                                                          int* __restrict__ cb_e,
                                                          int* __restrict__ cb_n) {
    __shared__ int tmp[256];
    int tid = threadIdx.x;
    int v = (tid < NB) ? cc_e[tid] : 0;
    tmp[tid] = v;
    __syncthreads();
    for (int off = 1; off < 256; off <<= 1) {
        int t = (tid >= off) ? tmp[tid - off] : 0;
        __syncthreads();
        tmp[tid] += t;
        __syncthreads();
    }
    if (tid < NB) cb_e[tid + 1] = tmp[tid];
    if (tid == 0) cb_e[0] = 0;
    __syncthreads();
    v = (tid < NB) ? cc_n[tid] : 0;
    tmp[tid] = v;
    __syncthreads();
    for (int off = 1; off < 256; off <<= 1) {
        int t = (tid >= off) ? tmp[tid - off] : 0;
        __syncthreads();
        tmp[tid] += t;
        __syncthreads();
    }
    if (tid < NB) cb_n[tid + 1] = tmp[tid];
    if (tid == 0) cb_n[0] = 0;
}

// pass 1: scatter into coarse buckets. Edge items carry the half-bit in the
// sort key: (v<<7) | (local_e*2 + (v>=NHALF)).
__global__ __launch_bounds__(256) void bucket_scatter_kernel(const int* __restrict__ node_idx,
                                                             const int* __restrict__ edge_idx,
                                                             const int* __restrict__ cb_e,
                                                             const int* __restrict__ cb_n,
                                                             int* __restrict__ cur_e,
                                                             int* __restrict__ cur_n,
                                                             int* __restrict__ buf_e,
                                                             int* __restrict__ buf_n) {
    __shared__ int he[NB], hn[NB], be[NB], bn[NB];
    int tid = threadIdx.x;
    int base = blockIdx.x * CHUNK;
    for (int i = tid; i < NB; i += 256) { he[i] = 0; hn[i] = 0; }
    __syncthreads();
    int pe[13], pn[13];   // (bucket<<12) | local_offset ; offset < 3125 < 4096
    #pragma unroll
    for (int k = 0; k < 13; k++) {
        int i = tid + k * 256;
        if (i < CHUNK) {
            int e = edge_idx[base + i], v = node_idx[base + i];
            int ke = e / EB_E, kn = v / EB_N;
            pe[k] = (ke << 12) | atomicAdd(&he[ke], 1);
            pn[k] = (kn << 12) | atomicAdd(&hn[kn], 1);
        }
    }
    __syncthreads();
    for (int k = tid; k < NB; k += 256) {
        int c = he[k];
        be[k] = cb_e[k] + (c ? atomicAdd(&cur_e[k], c) : 0);
        int cn = hn[k];
        bn[k] = cb_n[k] + (cn ? atomicAdd(&cur_n[k], cn) : 0);
    }
    __syncthreads();
    #pragma unroll
    for (int k = 0; k < 13; k++) {
        int i = tid + k * 256;
        if (i < CHUNK) {
            int e = edge_idx[base + i], v = node_idx[base + i];
            int ke = pe[k] >> 12, oe = pe[k] & 4095;
            buf_e[be[ke] + oe] = (v << 7) | ((e - ke * EB_E) * 2 + (v >= NHALF ? 1 : 0));
            int kn = pn[k] >> 12, on = pn[k] & 4095;
            buf_n[bn[kn] + on] = (e << 8) | (v - kn * EB_N);
        }
    }
}

// pass 2: per-bucket LDS counting sort -> PADDED CSR. Edge side: 80 bins
// (row, half) so each row is [half0 | pad8 | half1 | pad8]; emits rs (half0
// base) + deg0/deg1. Node side: rows 8-padded, deg_n. Pad rows' degs are
// written explicitly by the last block of each side (no pre-zeroing needed).
__global__ __launch_bounds__(256) void bucket_sort_kernel(const int* __restrict__ buf_e,
                                                          const int* __restrict__ buf_n,
                                                          const int* __restrict__ cb_e,
                                                          const int* __restrict__ cb_n,
                                                          unsigned short* __restrict__ csr_e,
                                                          unsigned short* __restrict__ csr_n,
                                                          int* __restrict__ rs_e,
                                                          int* __restrict__ rs_n,
                                                          int* __restrict__ deg_e0,
                                                          int* __restrict__ deg_e1,
                                                          int* __restrict__ deg_n) {
    __shared__ int A[CAP];
    __shared__ int h[EB_N], bs[EB_N], cs[EB_N];
    int tid = threadIdx.x;
    bool edgeSide = blockIdx.x < NB;
    int k = edgeSide ? blockIdx.x : blockIdx.x - NB;
    int rows = edgeSide ? EB_E : EB_N;
    int bins = edgeSide ? 2 * EB_E : EB_N;
    int shift = edgeSide ? 7 : 8;
    int mask = (1 << shift) - 1;
    int mp = edgeSide ? MP_E : MP_N;
    int sent = edgeSide ? N_NODES : N_EDGES;
    const int* cb  = edgeSide ? cb_e : cb_n;
    const int* buf = edgeSide ? buf_e : buf_n;
    unsigned short* csr = edgeSide ? csr_e : csr_n;
    int* rs  = edgeSide ? rs_e : rs_n;
    int base = cb[k];                               // exact base (buf reads)
    int base_pad = (base + k * mp + 7) & ~7;        // 8-aligned padded base (csr writes)
    int cnt = cb[k + 1] - base;
    for (int i = tid; i < bins; i += 256) h[i] = 0;
    __syncthreads();
    for (int i = tid; i < cnt; i += 256) {
        int it = buf[base + i];
        if (i < CAP) A[i] = it;
        atomicAdd(&h[it & mask], 1);
    }
    __syncthreads();
    if (tid == 0) {
        int s = 0;
        for (int j = 0; j < bins; j++) { bs[j] = s; s += (h[j] + 7) & ~7; }
    }
    __syncthreads();
    for (int j = tid; j < bins; j += 256) { cs[j] = h[j]; h[j] = 0; }
    __syncthreads();
    for (int j = tid; j < rows; j += 256) {
        if (edgeSide) {
            rs[k * EB_E + j] = base_pad + bs[2 * j];
            deg_e0[k * EB_E + j] = cs[2 * j];
            deg_e1[k * EB_E + j] = cs[2 * j + 1];
        } else {
            rs[k * EB_N + j] = base_pad + bs[j];
            deg_n[k * EB_N + j] = cs[j];
        }
    }
    if (k == NB - 1) {
        if (tid == 0) rs[edgeSide ? N_EDGES : N_NODES] = NNZ;
        if (edgeSide) {
            if (tid < MPAD - N_EDGES) { deg_e0[N_EDGES + tid] = 0; deg_e1[N_EDGES + tid] = 0; }
        } else {
            for (int x = tid; x < KTOT - N_NODES; x += 256) deg_n[N_NODES + x] = 0;
        }
    }
    __syncthreads();
    // fill pad slots with sentinel (disjoint from scatter slots)
    for (int j = tid; j < bins; j += 256) {
        int c0 = cs[j], e0 = (c0 + 7) & ~7;
        for (int x = c0; x < e0; x++) csr[base_pad + bs[j] + x] = (unsigned short)sent;
    }
    for (int i = tid; i < cnt; i += 256) {
        int it = (i < CAP) ? A[i] : buf[base + i];
        int loc = it & mask;
        int off = bs[loc] + atomicAdd(&h[loc], 1);
        csr[base_pad + off] = (unsigned short)(it >> shift);
    }
}

// Edge aggregation, 8 partitions = 4 ch-slices x 2 node-halves (3.2MB each,
// one per XCD). Each 8-lane group owns an edge and scans ONLY its half's
// pre-sorted sub-range: unconditional 128B gathers, zero masked waste, no
// cross-lane reduction. Writes bf16 PARTIAL sums e_accP[half][MPAD][256].
__global__ __launch_bounds__(256) void edge_aggregate_kernel(const uint4* __restrict__ embh4,
                                                             const unsigned short* __restrict__ csr_e,
                                                             const int* __restrict__ rs_e,
                                                             const int* __restrict__ deg_e0,
                                                             const int* __restrict__ deg_e1,
                                                             unsigned short* __restrict__ e_accp) {
    int sid = blockIdx.x & 7, g = blockIdx.x >> 3;  // g in [0, 314)
    int cslice = sid & 3, half = sid >> 2;
    const uint4* __restrict__ csr4 = (const uint4*)csr_e;
    int tid = threadIdx.x;
    int group = tid >> 3, l8 = tid & 7;
    const uint4* __restrict__ tbl = embh4 + (size_t)cslice * 50001 * 8 + l8;
    int e = g * 32 + group;                         // < MPAD (314*32 = 10048)
    int s = rs_e[min(e, N_EDGES)];
    int d0 = deg_e0[e], d1 = deg_e1[e];             // pad rows: 0 -> loop skipped
    int start = half ? s + ((d0 + 7) & ~7) : s;
    int dgh = half ? d1 : d0;
    int c0 = start >> 3, nc = (dgh + 7) >> 3;
    float a[8] = {0.f, 0.f, 0.f, 0.f, 0.f, 0.f, 0.f, 0.f};
    for (int c = c0; c < c0 + nc; c++) {
        uint4 pk = csr4[c];                         // broadcast across the 8 lanes
        int ix[8];
        idx8(pk, ix);
        #pragma unroll
        for (int j = 0; j < 8; j++) acc_bf8(tbl[(size_t)ix[j] * 8], a);
    }
    uint4 o;
    o.x = f2bf(a[0]) | ((unsigned)f2bf(a[1]) << 16);
    o.y = f2bf(a[2]) | ((unsigned)f2bf(a[3]) << 16);
    o.z = f2bf(a[4]) | ((unsigned)f2bf(a[5]) << 16);
    o.w = f2bf(a[6]) | ((unsigned)f2bf(a[7]) << 16);
    *(uint4*)(e_accp + ((size_t)half * MPAD + e) * C + cslice * 64 + l8 * 8) = o;
}

// e2[m][n] = Binv[m] * sum_k (e_accP0+e_accP1)[m][k] * conv_w[n][k] via MFMA;
// grid (157,4); output SLICE-MAJOR [4][MPAD][64ch]; pad rows ZERO.
__global__ __launch_bounds__(256) void edge_gemm_mfma_kernel(const unsigned short* __restrict__ e_accp,
                                                             const unsigned short* __restrict__ cwh,
                                                             const int* __restrict__ deg_e0,
                                                             const int* __restrict__ deg_e1,
                                                             unsigned short* __restrict__ e2h) {
    __shared__ __align__(16) unsigned short As[64 * 72];
    __shared__ __align__(16) unsigned short Bs[64 * 72];
    int i0 = blockIdx.x * 64, j0 = blockIdx.y * 64;
    int tid = threadIdx.x;
    int w = tid >> 6, lane = tid & 63;
    int col = lane & 15, quad = lane >> 4;
    floatx4 acc[4] = {};
    for (int step = 0; step < 4; step++) {
        int kb = step * 64;
        __syncthreads();
        #pragma unroll
        for (int l = 0; l < 2; l++) {
            int slot = tid + l * 256;
            int row = slot >> 3, grp = slot & 7;
            uint4 d0 = *(const uint4*)(e_accp + (size_t)(i0 + row) * C + kb + grp * 8);
            uint4 d1 = *(const uint4*)(e_accp + ((size_t)MPAD + i0 + row) * C + kb + grp * 8);
            *(uint4*)(&As[row * 72 + grp * 8]) = bfadd8(d0, d1);   // combine halves
            uint4 db = *(const uint4*)(cwh + (size_t)(j0 + row) * C + kb + grp * 8);
            *(uint4*)(&Bs[row * 72 + grp * 8]) = db;
        }
        __syncthreads();
        #pragma unroll
        for (int sub = 0; sub < 2; sub++) {
            short8 a = *(const short8*)(&As[(w * 16 + col) * 72 + sub * 32 + quad * 8]);
            #pragma unroll
            for (int jt = 0; jt < 4; jt++) {
                short8 b = *(const short8*)(&Bs[(jt * 16 + col) * 72 + sub * 32 + quad * 8]);
                acc[jt] = __builtin_amdgcn_mfma_f32_16x16x32_bf16(a, b, acc[jt], 0, 0, 0);
            }
        }
    }
    #pragma unroll
    for (int r = 0; r < 4; r++) {
        int m = i0 + w * 16 + quad * 4 + r;          // < MPAD always
        int dg = deg_e0[m] + deg_e1[m];              // pad rows: 0
        float binv = (dg > 0) ? 1.0f / (float)dg : 0.0f;
        #pragma unroll
        for (int jt = 0; jt < 4; jt++) {
            int ch = j0 + jt * 16 + col;
            e2h[(size_t)((ch >> 6) * MPAD + m) * 64 + (ch & 63)] = f2bf(acc[jt][r] * binv);
        }
    }
}

// XCD-sliced node aggregation (R10 proven), 64-CHANNEL slices (4 slices,
// table 1.28MB, L2-resident): each 8-lane group owns a node; lanes cover
// one contiguous 128B row. Broadcast csr chunk; unconditional unpack.
// Fused Dinv/bias/lrelu; LDS transpose; 16B yT stores.
__global__ __launch_bounds__(256) void node_aggregate_t_kernel(const uint4* __restrict__ e2h4,
                                                               const unsigned short* __restrict__ csr_n,
                                                               const int* __restrict__ rs_n,
                                                               const int* __restrict__ deg_n,
                                                               const float* __restrict__ conv_b,
                                                               unsigned short* __restrict__ yT) {
    __shared__ unsigned short T[64][33];   // [slice-ch][node-local], stride 33
    int sid = blockIdx.x & 3, g = blockIdx.x >> 2;
    const uint4* __restrict__ csr4 = (const uint4*)csr_n;
    int tid = threadIdx.x;
    int group = tid >> 3, l8 = tid & 7;
    const uint4* __restrict__ tbl = e2h4 + (size_t)sid * MPAD * 8 + l8;
    int n = g * 32 + group;                         // < KTOT (1568*32 = 50176)
    int s = rs_n[min(n, N_NODES)];
    int dg = deg_n[n];
    int c0 = s >> 3, nc = (dg + 7) >> 3;
    float4 b0 = ((const float4*)conv_b)[sid * 16 + l8 * 2];
    float4 b1 = ((const float4*)conv_b)[sid * 16 + l8 * 2 + 1];
    float a[8] = {0.f, 0.f, 0.f, 0.f, 0.f, 0.f, 0.f, 0.f};
    for (int c = c0; c < c0 + nc; c++) {
        uint4 pk = csr4[c];                         // broadcast across the 8 lanes
        int ix[8];
        idx8(pk, ix);
        #pragma unroll
        for (int j = 0; j < 8; j++) acc_bf8(tbl[(size_t)ix[j] * 8], a);
    }
    float dinv = (dg > 0) ? 1.0f / (float)dg : 0.0f;
    float bb[8] = {b0.x, b0.y, b0.z, b0.w, b1.x, b1.y, b1.z, b1.w};
    #pragma unroll
    for (int jj = 0; jj < 8; jj++) {
        float r = a[jj] * dinv + bb[jj];
        r = (r > 0.f) ? r : SLOPE * r;
        if (n >= N_NODES) r = 0.f;                 // zero-pad rows for gram
        T[l8 * 8 + jj][group] = f2bf(r);
    }
    __syncthreads();
    int rr = tid >> 2, cc = tid & 3;               // 64 rows x 4 packers
    uint4 o;
    o.x = T[rr][cc * 8 + 0] | ((unsigned)T[rr][cc * 8 + 1] << 16);
    o.y = T[rr][cc * 8 + 2] | ((unsigned)T[rr][cc * 8 + 3] << 16);
    o.z = T[rr][cc * 8 + 4] | ((unsigned)T[rr][cc * 8 + 5] << 16);
    o.w = T[rr][cc * 8 + 6] | ((unsigned)T[rr][cc * 8 + 7] << 16);
    *(uint4*)(yT + (size_t)(sid * 64 + rr) * KTOT + g * 32 + cc * 8) = o;
}

// Gram partials via MFMA, symmetry-aware (10 upper-tri tile pairs), NO atomics.
__global__ __launch_bounds__(256) void gram_mfma_kernel(const unsigned short* __restrict__ yT,
                                                        float* __restrict__ part) {
    static const int PI[10] = {0, 0, 0, 0, 1, 1, 1, 2, 2, 3};
    static const int PJ[10] = {0, 1, 2, 3, 1, 2, 3, 2, 3, 3};
    __shared__ __align__(16) unsigned short As[64 * 72];  // [col][k], stride 72
    __shared__ __align__(16) unsigned short Bs[64 * 72];
    int i0 = PI[blockIdx.x] * 64, j0 = PJ[blockIdx.x] * 64;
    bool diag = (i0 == j0);
    int kb0 = blockIdx.y * KCHUNK;
    int tid = threadIdx.x;
    int w = tid >> 6, lane = tid & 63;
    int col = lane & 15, quad = lane >> 4;
    floatx4 acc[4] = {};
    for (int step = 0; step < KCHUNK / 64; step++) {
        int kb = kb0 + step * 64;
        __syncthreads();
        #pragma unroll
        for (int l = 0; l < 2; l++) {
            int slot = tid + l * 256;
            int row = slot >> 3, grp = slot & 7;
            uint4 da = *(const uint4*)(yT + (size_t)(i0 + row) * KTOT + kb + grp * 8);
            *(uint4*)(&As[row * 72 + grp * 8]) = da;
            if (!diag) {
                uint4 db = *(const uint4*)(yT + (size_t)(j0 + row) * KTOT + kb + grp * 8);
                *(uint4*)(&Bs[row * 72 + grp * 8]) = db;
            }
        }
        __syncthreads();
        const unsigned short* Bb = diag ? As : Bs;
        #pragma unroll
        for (int sub = 0; sub < 2; sub++) {
            short8 a = *(const short8*)(&As[(w * 16 + col) * 72 + sub * 32 + quad * 8]);
            #pragma unroll
            for (int jt = 0; jt < 4; jt++) {
                short8 b = *(const short8*)(&Bb[(jt * 16 + col) * 72 + sub * 32 + quad * 8]);
                acc[jt] = __builtin_amdgcn_mfma_f32_16x16x32_bf16(a, b, acc[jt], 0, 0, 0);
            }
        }
    }
    float* slab = part + ((size_t)blockIdx.y * 10 + blockIdx.x) * 4096;
    #pragma unroll
    for (int jt = 0; jt < 4; jt++)
        #pragma unroll
        for (int r = 0; r < 4; r++)
            slab[(w * 16 + quad * 4 + r) * 64 + jt * 16 + col] = acc[jt][r];
}

// FUSED: block i reduces g row i from the 98 partial slabs (with symmetric
// mirror) into LDS, then computes out row i = lrelu(g_row @ lin_w^T + lin_b).
__global__ __launch_bounds__(256) void greduce_out_kernel(const float* __restrict__ part,
                                                          const float* __restrict__ lin_w,
                                                          const float* __restrict__ lin_b,
                                                          float* __restrict__ out) {
    __shared__ float gs[C];
    int i = blockIdx.x, j = threadIdx.x;
    int a = i >> 6, b = j >> 6;
    int lo = min(a, b), hi = max(a, b);
    int t = lo * (7 - lo) / 2 + hi;          // pair index in PI/PJ order
    int li = (a <= b) ? (i & 63) : (j & 63);
    int lj = (a <= b) ? (j & 63) : (i & 63);
    const float* p = part + (size_t)t * 4096 + li * 64 + lj;
    float s = 0.f;
    for (int z = 0; z < NZB; z++) s += p[(size_t)z * 40960];
    gs[j] = s;
    __syncthreads();
    float acc = lin_b[j];
    const float* wrow = lin_w + (size_t)j * C;
    for (int k = 0; k < C; k++) acc += gs[k] * wrow[k];
    out[(size_t)i * C + j] = (acc > 0.f) ? acc : SLOPE * acc;
}

extern "C" void kernel_launch(void* const* d_in, const int* in_sizes, int n_in,
                              void* d_out, int out_size, void* d_ws, size_t ws_size,
                              hipStream_t stream) {
    const float* emb    = (const float*)d_in[0];
    const float* conv_w = (const float*)d_in[1];
    const float* conv_b = (const float*)d_in[2];
    const float* lin_w  = (const float*)d_in[3];
    const float* lin_b  = (const float*)d_in[4];
    const int*   eidx   = (const int*)d_in[5];
    const int* node_idx = eidx;        // edge_index[0]
    const int* edge_idx = eidx + NNZ;  // edge_index[1]

    char* ws = (char*)d_ws;
    int* cc_e  = (int*)(ws + OFF_CC_E);
    int* cc_n  = (int*)(ws + OFF_CC_N);
    int* cur_e = (int*)(ws + OFF_CUR_E);
    int* cur_n = (int*)(ws + OFF_CUR_N);
    int* deg_e0 = (int*)(ws + OFF_DEG_E0);
    int* deg_e1 = (int*)(ws + OFF_DEG_E1);
    int* deg_n = (int*)(ws + OFF_DEG_N);
    int* cb_e  = (int*)(ws + OFF_CB_E);
    int* cb_n  = (int*)(ws + OFF_CB_N);
    int* rs_n  = (int*)(ws + OFF_RS_N);
    int* rs_e  = (int*)(ws + OFF_RS_E);
    int* buf_e = (int*)(ws + OFF_BUF_E);
    int* buf_n = (int*)(ws + OFF_BUF_N);
    unsigned short* csr_e = (unsigned short*)(ws + OFF_CSR_E);
    unsigned short* csr_n = (unsigned short*)(ws + OFF_CSR_N);
    uint4* embh4 = (uint4*)(ws + OFF_EMBH);
    unsigned short* e_accp = (unsigned short*)(ws + OFF_EACCP);
    unsigned short* e2h = (unsigned short*)(ws + OFF_E2);
    unsigned short* cwh = (unsigned short*)(ws + OFF_CWH);
    unsigned short* yT  = (unsigned short*)(ws + OFF_YT);
    float* part = (float*)(ws + OFF_PART);
    float* out = (float*)d_out;

    zero_kernel<<<1, 256, 0, stream>>>((float4*)ws, ZERO_BYTES / 16);

    prep_kernel<<<PREP_EMB_BLOCKS + PREP_CW_BLOCKS + 256, 256, 0, stream>>>(
        (const float4*)emb, embh4, (const float4*)conv_w, (uint4*)cwh,
        node_idx, edge_idx, cc_e, cc_n);

    coarse_scan_kernel<<<1, 256, 0, stream>>>(cc_e, cc_n, cb_e, cb_n);

    bucket_scatter_kernel<<<256, 256, 0, stream>>>(node_idx, edge_idx, cb_e, cb_n,
                                                   cur_e, cur_n, buf_e, buf_n);

    bucket_sort_kernel<<<2 * NB, 256, 0, stream>>>(buf_e, buf_n, cb_e, cb_n,
                                                   csr_e, csr_n, rs_e, rs_n,
                                                   deg_e0, deg_e1, deg_n);

    edge_aggregate_kernel<<<8 * EAGG_G, 256, 0, stream>>>(embh4, csr_e, rs_e,
                                                          deg_e0, deg_e1, e_accp);

    edge_gemm_mfma_kernel<<<dim3(MPAD / 64, C / 64), 256, 0, stream>>>(e_accp, cwh,
                                                                       deg_e0, deg_e1, e2h);

    node_aggregate_t_kernel<<<4 * NAGG_G, 256, 0, stream>>>((const uint4*)e2h, csr_n, rs_n,
                                                            deg_n, conv_b, yT);

    gram_mfma_kernel<<<dim3(10, NZB), 256, 0, stream>>>(yT, part);

    greduce_out_kernel<<<C, 256, 0, stream>>>(part, lin_w, lin_b, out);
}

// Round 13
// 249.688 us; speedup vs baseline: 1.1988x; 1.0361x over previous
//
#include <hip/hip_runtime.h>

#define N_NODES 50000
#define N_EDGES 10000
#define NNZ     800000
#define C       256
#define SLOPE   0.01f
#define KTOT    50176   // node count padded to 512*98
#define KCHUNK2 1024    // gram: 2 x 512 chunks per block
#define NZB2    49      // KTOT / KCHUNK2
#define MPAD    10048   // edge count padded to multiple of 64
#define NHALF   25000   // node-id half boundary (edge-side partitions)

#define NB      250     // coarse buckets per side
#define EB_E    40      // edges per bucket   (250*40  = 10000)
#define EB_N    200     // nodes per bucket   (250*200 = 50000)
#define CHUNK   3125    // NNZ / 256 blocks
#define CAP     6000    // LDS item capacity in bucket_sort (mean 3200, sd ~57)
#define OCAP    5376    // LDS staged-output capacity (ushorts); psz <= ~4800
#define MP_E    576     // per-bucket pad slack, edge side (80 bins * 7 + align 8)
#define MP_N    1408    // per-bucket pad slack, node side (200 rows * 7 + align 8)

#define EAGG_G  314     // edge-agg blocks per partition (314*32 = 10048 = MPAD), 8 parts
#define NAGG_G  1568    // node-agg blocks per slice (1568*32 = 50176 = KTOT), 4 slices

// ---- workspace layout (bytes) ----
#define OFF_CC_E    0          // 250*4 coarse counts (edge)
#define OFF_CC_N    1024       // 250*4 coarse counts (node)
#define OFF_CUR_E   2048       // 250*4 scatter cursors
#define OFF_CUR_N   3072       // 250*4
#define ZERO_BYTES  4096       // zeroed via hipMemsetAsync (counters only)
#define OFF_DEG_E0  4096       // 10048*4 half-0 degrees -> 44288
#define OFF_DEG_E1  45056      // 10048*4 half-1 degrees -> 85248
#define OFF_DEG_N   86016      // 50176*4 node degrees -> 286720
#define OFF_RS_N    290816     // 50001*4 PADDED row starts -> 490820
#define OFF_RS_E    491520     // 10001*4 PADDED row starts (half0 base) -> 531524
#define OFF_BUF_E   532480     // 800000*4 bucketed items (edge side)
#define OFF_BUF_N   3732480    // 800000*4 bucketed items (node side)
#define OFF_CSR_E   6932480    // <=944000*2 ushort node ids, per-HALF 8-padded
#define OFF_CSR_N   8820480    // <=1152000*2 ushort edge ids, rows 8-padded
#define OFF_EMBH    13308672   // SLICE-MAJOR [4][50001][64ch] bf16 (node 50000 zero)
#define OFF_YT      13308672   // 256*50176*2 bf16 — ALIASES embh (embh dead before
                               // node_aggregate writes yT); ends 38,998,784
#define OFF_E2      44144640   // SLICE-MAJOR [4][10048][64ch] bf16; rows >=10000 ZERO
#define OFF_CWH     49289216   // 256*256*2 bf16 conv_w
#define OFF_PART    49420288   // 49*10*4096*4 gram partials -> 57,448,448
#define OFF_EACCP   OFF_PART   // ALIASES part: [2][10048][256] bf16 edge partial sums

typedef __attribute__((ext_vector_type(8))) short short8;
typedef __attribute__((ext_vector_type(4))) float floatx4;

static __device__ __forceinline__ unsigned short f2bf(float f) {
    unsigned int u = __float_as_uint(f);
    u = (u + 0x7fffu + ((u >> 16) & 1u)) >> 16;   // RNE
    return (unsigned short)u;
}

// unpack uint4 (8 bf16) and accumulate into a[0..7]
static __device__ __forceinline__ void acc_bf8(const uint4 d, float* a) {
    a[0] += __uint_as_float(d.x << 16);
    a[1] += __uint_as_float(d.x & 0xffff0000u);
    a[2] += __uint_as_float(d.y << 16);
    a[3] += __uint_as_float(d.y & 0xffff0000u);
    a[4] += __uint_as_float(d.z << 16);
    a[5] += __uint_as_float(d.z & 0xffff0000u);
    a[6] += __uint_as_float(d.w << 16);
    a[7] += __uint_as_float(d.w & 0xffff0000u);
}

// extract 8 ushort indices from one uint4 (16B of csr)
static __device__ __forceinline__ void idx8(const uint4 pk, int* ix) {
    ix[0] = (int)(pk.x & 0xffffu); ix[1] = (int)(pk.x >> 16);
    ix[2] = (int)(pk.y & 0xffffu); ix[3] = (int)(pk.y >> 16);
    ix[4] = (int)(pk.z & 0xffffu); ix[5] = (int)(pk.z >> 16);
    ix[6] = (int)(pk.w & 0xffffu); ix[7] = (int)(pk.w >> 16);
}

// bf16 pairwise add of two packed-bf16 words / uint4s (via f32)
static __device__ __forceinline__ unsigned bfadd2(unsigned x, unsigned y) {
    float lx = __uint_as_float(x << 16), hx = __uint_as_float(x & 0xffff0000u);
    float ly = __uint_as_float(y << 16), hy = __uint_as_float(y & 0xffff0000u);
    return (unsigned)f2bf(lx + ly) | ((unsigned)f2bf(hx + hy) << 16);
}
static __device__ __forceinline__ uint4 bfadd8(uint4 x, uint4 y) {
    x.x = bfadd2(x.x, y.x); x.y = bfadd2(x.y, y.y);
    x.z = bfadd2(x.z, y.z); x.w = bfadd2(x.w, y.w);
    return x;
}

// FUSED prep: blocks [0,6251) cast emb->bf16 SLICE-MAJOR [4][50001][64ch],
// [6251,6283) cast conv_w->bf16, [6283,6539) coarse histogram.
#define PREP_EMB_BLOCKS 6251
#define PREP_CW_BLOCKS  32
__global__ __launch_bounds__(256) void prep_kernel(const float4* __restrict__ emb4,
                                                   uint4* __restrict__ embh4,
                                                   const float4* __restrict__ cw4,
                                                   uint4* __restrict__ cwh4,
                                                   const int* __restrict__ node_idx,
                                                   const int* __restrict__ edge_idx,
                                                   int* __restrict__ cc_e,
                                                   int* __restrict__ cc_n) {
    __shared__ int he[NB], hn[NB];
    int b = blockIdx.x, tid = threadIdx.x;
    if (b < PREP_EMB_BLOCKS) {
        int i = b * 256 + tid;
        if (i >= 1600032) return;
        uint4 o = {0u, 0u, 0u, 0u};
        if (i < 1600000) {
            float4 f0 = emb4[2 * i], f1 = emb4[2 * i + 1];
            o.x = f2bf(f0.x) | ((unsigned)f2bf(f0.y) << 16);
            o.y = f2bf(f0.z) | ((unsigned)f2bf(f0.w) << 16);
            o.z = f2bf(f1.x) | ((unsigned)f2bf(f1.y) << 16);
            o.w = f2bf(f1.z) | ((unsigned)f2bf(f1.w) << 16);
        }
        // slice-major 64ch: node = i>>5, chunk c = i&31 (8 ch each),
        // slice = c>>3 (4 slices of 8 uint4), pos = c&7
        int node = i >> 5, c = i & 31;
        embh4[((size_t)(c >> 3) * 50001 + node) * 8 + (c & 7)] = o;
    } else if (b < PREP_EMB_BLOCKS + PREP_CW_BLOCKS) {
        int i = (b - PREP_EMB_BLOCKS) * 256 + tid;   // < 8192
        float4 f0 = cw4[2 * i], f1 = cw4[2 * i + 1];
        uint4 o;
        o.x = f2bf(f0.x) | ((unsigned)f2bf(f0.y) << 16);
        o.y = f2bf(f0.z) | ((unsigned)f2bf(f0.w) << 16);
        o.z = f2bf(f1.x) | ((unsigned)f2bf(f1.y) << 16);
        o.w = f2bf(f1.z) | ((unsigned)f2bf(f1.w) << 16);
        cwh4[i] = o;
    } else {
        int base = (b - PREP_EMB_BLOCKS - PREP_CW_BLOCKS) * CHUNK;
        for (int i = tid; i < NB; i += 256) { he[i] = 0; hn[i] = 0; }
        __syncthreads();
        for (int i = tid; i < CHUNK; i += 256) {
            atomicAdd(&he[edge_idx[base + i] / EB_E], 1);
            atomicAdd(&hn[node_idx[base + i] / EB_N], 1);
        }
        __syncthreads();
        for (int k = tid; k < NB; k += 256) {
            if (he[k]) atomicAdd(&cc_e[k], he[k]);
            if (hn[k]) atomicAdd(&cc_n[k], hn[k]);
        }
    }
}

// pass 1: scatter into coarse buckets. Coarse bases computed IN-BLOCK via a
// 250-element LDS scan of cc (identical in every block; replaces the old
// single-block coarse_scan kernel). Edge items carry the half-bit:
// (v<<7) | (local_e*2 + (v>=NHALF)).
__global__ __launch_bounds__(256) void bucket_scatter_kernel(const int* __restrict__ node_idx,
                                                             const int* __restrict__ edge_idx,
                                                             const int* __restrict__ cc_e,
                                                             const int* __restrict__ cc_n,
                                                             int* __restrict__ cur_e,
                                                             int* __restrict__ cur_n,
                                                             int* __restrict__ buf_e,
                                                             int* __restrict__ buf_n) {
    __shared__ int he[NB], hn[NB], be[NB], bn[NB];
    __shared__ int cbl_e[NB], cbl_n[NB], tmp[256];
    int tid = threadIdx.x;
    int base = blockIdx.x * CHUNK;
    // exclusive scans of cc_e / cc_n
    int v = (tid < NB) ? cc_e[tid] : 0;
    tmp[tid] = v;
    __syncthreads();
    for (int off = 1; off < 256; off <<= 1) {
        int t = (tid >= off) ? tmp[tid - off] : 0;
        __syncthreads();
        tmp[tid] += t;
        __syncthreads();
    }
    if (tid < NB) cbl_e[tid] = tmp[tid] - v;
    __syncthreads();
    v = (tid < NB) ? cc_n[tid] : 0;
    tmp[tid] = v;
    __syncthreads();
    for (int off = 1; off < 256; off <<= 1) {
        int t = (tid >= off) ? tmp[tid - off] : 0;
        __syncthreads();
        tmp[tid] += t;
        __syncthreads();
    }
    if (tid < NB) cbl_n[tid] = tmp[tid] - v;
    for (int i = tid; i < NB; i += 256) { he[i] = 0; hn[i] = 0; }
    __syncthreads();
    int pe[13], pn[13];   // (bucket<<12) | local_offset ; offset < 3125 < 4096
    #pragma unroll
    for (int k = 0; k < 13; k++) {
        int i = tid + k * 256;
        if (i < CHUNK) {
            int e = edge_idx[base + i], v2 = node_idx[base + i];
            int ke = e / EB_E, kn = v2 / EB_N;
            pe[k] = (ke << 12) | atomicAdd(&he[ke], 1);
            pn[k] = (kn << 12) | atomicAdd(&hn[kn], 1);
        }
    }
    __syncthreads();
    for (int k = tid; k < NB; k += 256) {
        int c = he[k];
        be[k] = cbl_e[k] + (c ? atomicAdd(&cur_e[k], c) : 0);
        int cn = hn[k];
        bn[k] = cbl_n[k] + (cn ? atomicAdd(&cur_n[k], cn) : 0);
    }
    __syncthreads();
    #pragma unroll
    for (int k = 0; k < 13; k++) {
        int i = tid + k * 256;
        if (i < CHUNK) {
            int e = edge_idx[base + i], v2 = node_idx[base + i];
            int ke = pe[k] >> 12, oe = pe[k] & 4095;
            buf_e[be[ke] + oe] = (v2 << 7) | ((e - ke * EB_E) * 2 + (v2 >= NHALF ? 1 : 0));
            int kn = pn[k] >> 12, on = pn[k] & 4095;
            buf_n[bn[kn] + on] = (e << 8) | (v2 - kn * EB_N);
        }
    }
}

// pass 2: per-bucket LDS counting sort -> PADDED CSR. Edge side: 80 bins
// (row, half); node side: 200 rows 8-padded. Output is STAGED in LDS and
// streamed out as coalesced 16B stores (guarded fallback to direct writes).
// Coarse base recomputed in-block via LDS scan of cc.
__global__ __launch_bounds__(256) void bucket_sort_kernel(const int* __restrict__ buf_e,
                                                          const int* __restrict__ buf_n,
                                                          const int* __restrict__ cc_e,
                                                          const int* __restrict__ cc_n,
                                                          unsigned short* __restrict__ csr_e,
                                                          unsigned short* __restrict__ csr_n,
                                                          int* __restrict__ rs_e,
                                                          int* __restrict__ rs_n,
                                                          int* __restrict__ deg_e0,
                                                          int* __restrict__ deg_e1,
                                                          int* __restrict__ deg_n) {
    __shared__ int A[CAP];
    __shared__ unsigned short O[OCAP];
    __shared__ int h[EB_N], bs[EB_N], cs[EB_N];
    __shared__ int tmp[256];
    int tid = threadIdx.x;
    bool edgeSide = blockIdx.x < NB;
    int k = edgeSide ? blockIdx.x : blockIdx.x - NB;
    int rows = edgeSide ? EB_E : EB_N;
    int bins = edgeSide ? 2 * EB_E : EB_N;
    int shift = edgeSide ? 7 : 8;
    int mask = (1 << shift) - 1;
    int mp = edgeSide ? MP_E : MP_N;
    int sent = edgeSide ? N_NODES : N_EDGES;
    const int* cc  = edgeSide ? cc_e : cc_n;
    const int* buf = edgeSide ? buf_e : buf_n;
    unsigned short* csr = edgeSide ? csr_e : csr_n;
    int* rs  = edgeSide ? rs_e : rs_n;
    // in-block exclusive scan of cc -> this bucket's exact base
    int vv = (tid < NB) ? cc[tid] : 0;
    tmp[tid] = vv;
    __syncthreads();
    for (int off = 1; off < 256; off <<= 1) {
        int t = (tid >= off) ? tmp[tid - off] : 0;
        __syncthreads();
        tmp[tid] += t;
        __syncthreads();
    }
    __shared__ int baseSh;
    if (tid == k) baseSh = tmp[k] - vv;
    __syncthreads();
    int base = baseSh;                              // exact base (buf reads)
    int base_pad = (base + k * mp + 7) & ~7;        // 8-aligned padded base (csr writes)
    int cnt = cc[k];
    for (int i = tid; i < bins; i += 256) h[i] = 0;
    __syncthreads();
    for (int i = tid; i < cnt; i += 256) {
        int it = buf[base + i];
        if (i < CAP) A[i] = it;
        atomicAdd(&h[it & mask], 1);
    }
    __syncthreads();
    if (tid == 0) {
        int s = 0;
        for (int j = 0; j < bins; j++) { bs[j] = s; s += (h[j] + 7) & ~7; }
    }
    __syncthreads();
    for (int j = tid; j < bins; j += 256) { cs[j] = h[j]; h[j] = 0; }
    __syncthreads();
    for (int j = tid; j < rows; j += 256) {
        if (edgeSide) {
            rs[k * EB_E + j] = base_pad + bs[2 * j];
            deg_e0[k * EB_E + j] = cs[2 * j];
            deg_e1[k * EB_E + j] = cs[2 * j + 1];
        } else {
            rs[k * EB_N + j] = base_pad + bs[j];
            deg_n[k * EB_N + j] = cs[j];
        }
    }
    if (k == NB - 1) {
        if (tid == 0) rs[edgeSide ? N_EDGES : N_NODES] = NNZ;
        if (edgeSide) {
            if (tid < MPAD - N_EDGES) { deg_e0[N_EDGES + tid] = 0; deg_e1[N_EDGES + tid] = 0; }
        } else {
            for (int x = tid; x < KTOT - N_NODES; x += 256) deg_n[N_NODES + x] = 0;
        }
    }
    __syncthreads();
    int psz = bs[bins - 1] + ((cs[bins - 1] + 7) & ~7);   // padded total size
    if (psz <= OCAP) {
        // staged path: sort into LDS, stream out coalesced 16B stores
        for (int s = tid; s < psz; s += 256) O[s] = (unsigned short)sent;
        __syncthreads();
        for (int i = tid; i < cnt; i += 256) {
            int it = (i < CAP) ? A[i] : buf[base + i];
            int loc = it & mask;
            int off = bs[loc] + atomicAdd(&h[loc], 1);
            O[off] = (unsigned short)(it >> shift);
        }
        __syncthreads();
        uint4* dst = (uint4*)(csr + base_pad);
        const uint4* src = (const uint4*)O;
        for (int s = tid; s * 8 < psz; s += 256) dst[s] = src[s];
    } else {
        // fallback: direct scattered writes
        for (int j = tid; j < bins; j += 256) {
            int c0 = cs[j], e0 = (c0 + 7) & ~7;
            for (int x = c0; x < e0; x++) csr[base_pad + bs[j] + x] = (unsigned short)sent;
        }
        for (int i = tid; i < cnt; i += 256) {
            int it = (i < CAP) ? A[i] : buf[base + i];
            int loc = it & mask;
            int off = bs[loc] + atomicAdd(&h[loc], 1);
            csr[base_pad + off] = (unsigned short)(it >> shift);
        }
    }
}

// Edge aggregation, 8 partitions = 4 ch-slices x 2 node-halves (3.2MB each,
// one per XCD). Each 8-lane group owns an edge and scans ONLY its half's
// pre-sorted sub-range: unconditional 128B gathers, zero masked waste, no
// cross-lane reduction. Writes bf16 PARTIAL sums e_accP[half][MPAD][256].
__global__ __launch_bounds__(256) void edge_aggregate_kernel(const uint4* __restrict__ embh4,
                                                             const unsigned short* __restrict__ csr_e,
                                                             const int* __restrict__ rs_e,
                                                             const int* __restrict__ deg_e0,
                                                             const int* __restrict__ deg_e1,
                                                             unsigned short* __restrict__ e_accp) {
    int sid = blockIdx.x & 7, g = blockIdx.x >> 3;  // g in [0, 314)
    int cslice = sid & 3, half = sid >> 2;
    const uint4* __restrict__ csr4 = (const uint4*)csr_e;
    int tid = threadIdx.x;
    int group = tid >> 3, l8 = tid & 7;
    const uint4* __restrict__ tbl = embh4 + (size_t)cslice * 50001 * 8 + l8;
    int e = g * 32 + group;                         // < MPAD (314*32 = 10048)
    int s = rs_e[min(e, N_EDGES)];
    int d0 = deg_e0[e], d1 = deg_e1[e];             // pad rows: 0 -> loop skipped
    int start = half ? s + ((d0 + 7) & ~7) : s;
    int dgh = half ? d1 : d0;
    int c0 = start >> 3, nc = (dgh + 7) >> 3;
    float a[8] = {0.f, 0.f, 0.f, 0.f, 0.f, 0.f, 0.f, 0.f};
    for (int c = c0; c < c0 + nc; c++) {
        uint4 pk = csr4[c];                         // broadcast across the 8 lanes
        int ix[8];
        idx8(pk, ix);
        #pragma unroll
        for (int j = 0; j < 8; j++) acc_bf8(tbl[(size_t)ix[j] * 8], a);
    }
    uint4 o;
    o.x = f2bf(a[0]) | ((unsigned)f2bf(a[1]) << 16);
    o.y = f2bf(a[2]) | ((unsigned)f2bf(a[3]) << 16);
    o.z = f2bf(a[4]) | ((unsigned)f2bf(a[5]) << 16);
    o.w = f2bf(a[6]) | ((unsigned)f2bf(a[7]) << 16);
    *(uint4*)(e_accp + ((size_t)half * MPAD + e) * C + cslice * 64 + l8 * 8) = o;
}

// e2[m][n] = Binv[m] * sum_k (e_accP0+e_accP1)[m][k] * conv_w[n][k] via MFMA;
// grid (157,4); output SLICE-MAJOR [4][MPAD][64ch]; pad rows ZERO.
__global__ __launch_bounds__(256) void edge_gemm_mfma_kernel(const unsigned short* __restrict__ e_accp,
                                                             const unsigned short* __restrict__ cwh,
                                                             const int* __restrict__ deg_e0,
                                                             const int* __restrict__ deg_e1,
                                                             unsigned short* __restrict__ e2h) {
    __shared__ __align__(16) unsigned short As[64 * 72];
    __shared__ __align__(16) unsigned short Bs[64 * 72];
    int i0 = blockIdx.x * 64, j0 = blockIdx.y * 64;
    int tid = threadIdx.x;
    int w = tid >> 6, lane = tid & 63;
    int col = lane & 15, quad = lane >> 4;
    floatx4 acc[4] = {};
    for (int step = 0; step < 4; step++) {
        int kb = step * 64;
        __syncthreads();
        #pragma unroll
        for (int l = 0; l < 2; l++) {
            int slot = tid + l * 256;
            int row = slot >> 3, grp = slot & 7;
            uint4 d0 = *(const uint4*)(e_accp + (size_t)(i0 + row) * C + kb + grp * 8);
            uint4 d1 = *(const uint4*)(e_accp + ((size_t)MPAD + i0 + row) * C + kb + grp * 8);
            *(uint4*)(&As[row * 72 + grp * 8]) = bfadd8(d0, d1);   // combine halves
            uint4 db = *(const uint4*)(cwh + (size_t)(j0 + row) * C + kb + grp * 8);
            *(uint4*)(&Bs[row * 72 + grp * 8]) = db;
        }
        __syncthreads();
        #pragma unroll
        for (int sub = 0; sub < 2; sub++) {
            short8 a = *(const short8*)(&As[(w * 16 + col) * 72 + sub * 32 + quad * 8]);
            #pragma unroll
            for (int jt = 0; jt < 4; jt++) {
                short8 b = *(const short8*)(&Bs[(jt * 16 + col) * 72 + sub * 32 + quad * 8]);
                acc[jt] = __builtin_amdgcn_mfma_f32_16x16x32_bf16(a, b, acc[jt], 0, 0, 0);
            }
        }
    }
    #pragma unroll
    for (int r = 0; r < 4; r++) {
        int m = i0 + w * 16 + quad * 4 + r;          // < MPAD always
        int dg = deg_e0[m] + deg_e1[m];              // pad rows: 0
        float binv = (dg > 0) ? 1.0f / (float)dg : 0.0f;
        #pragma unroll
        for (int jt = 0; jt < 4; jt++) {
            int ch = j0 + jt * 16 + col;
            e2h[(size_t)((ch >> 6) * MPAD + m) * 64 + (ch & 63)] = f2bf(acc[jt][r] * binv);
        }
    }
}

// XCD-sliced node aggregation, 64-CHANNEL slices (4 slices, table 1.28MB,
// L2-resident): each 8-lane group owns a node; lanes cover one contiguous
// 128B row. Broadcast csr chunk; unconditional unpack (rows 8-padded).
// Fused Dinv/bias/lrelu; LDS transpose; 16B yT stores.
__global__ __launch_bounds__(256) void node_aggregate_t_kernel(const uint4* __restrict__ e2h4,
                                                               const unsigned short* __restrict__ csr_n,
                                                               const int* __restrict__ rs_n,
                                                               const int* __restrict__ deg_n,
                                                               const float* __restrict__ conv_b,
                                                               unsigned short* __restrict__ yT) {
    __shared__ unsigned short T[64][33];   // [slice-ch][node-local], stride 33
    int sid = blockIdx.x & 3, g = blockIdx.x >> 2;
    const uint4* __restrict__ csr4 = (const uint4*)csr_n;
    int tid = threadIdx.x;
    int group = tid >> 3, l8 = tid & 7;
    const uint4* __restrict__ tbl = e2h4 + (size_t)sid * MPAD * 8 + l8;
    int n = g * 32 + group;                         // < KTOT (1568*32 = 50176)
    int s = rs_n[min(n, N_NODES)];
    int dg = deg_n[n];
    int c0 = s >> 3, nc = (dg + 7) >> 3;
    float4 b0 = ((const float4*)conv_b)[sid * 16 + l8 * 2];
    float4 b1 = ((const float4*)conv_b)[sid * 16 + l8 * 2 + 1];
    float a[8] = {0.f, 0.f, 0.f, 0.f, 0.f, 0.f, 0.f, 0.f};
    for (int c = c0; c < c0 + nc; c++) {
        uint4 pk = csr4[c];                         // broadcast across the 8 lanes
        int ix[8];
        idx8(pk, ix);
        #pragma unroll
        for (int j = 0; j < 8; j++) acc_bf8(tbl[(size_t)ix[j] * 8], a);
    }
    float dinv = (dg > 0) ? 1.0f / (float)dg : 0.0f;
    float bb[8] = {b0.x, b0.y, b0.z, b0.w, b1.x, b1.y, b1.z, b1.w};
    #pragma unroll
    for (int jj = 0; jj < 8; jj++) {
        float r = a[jj] * dinv + bb[jj];
        r = (r > 0.f) ? r : SLOPE * r;
        if (n >= N_NODES) r = 0.f;                 // zero-pad rows for gram
        T[l8 * 8 + jj][group] = f2bf(r);
    }
    __syncthreads();
    int rr = tid >> 2, cc = tid & 3;               // 64 rows x 4 packers
    uint4 o;
    o.x = T[rr][cc * 8 + 0] | ((unsigned)T[rr][cc * 8 + 1] << 16);
    o.y = T[rr][cc * 8 + 2] | ((unsigned)T[rr][cc * 8 + 3] << 16);
    o.z = T[rr][cc * 8 + 4] | ((unsigned)T[rr][cc * 8 + 5] << 16);
    o.w = T[rr][cc * 8 + 6] | ((unsigned)T[rr][cc * 8 + 7] << 16);
    *(uint4*)(yT + (size_t)(sid * 64 + rr) * KTOT + g * 32 + cc * 8) = o;
}

// Gram partials via MFMA, symmetry-aware (10 upper-tri tile pairs), NO atomics.
// grid (10, 49): each block accumulates 2 K-chunks -> half the partial slabs.
__global__ __launch_bounds__(256) void gram_mfma_kernel(const unsigned short* __restrict__ yT,
                                                        float* __restrict__ part) {
    static const int PI[10] = {0, 0, 0, 0, 1, 1, 1, 2, 2, 3};
    static const int PJ[10] = {0, 1, 2, 3, 1, 2, 3, 2, 3, 3};
    __shared__ __align__(16) unsigned short As[64 * 72];  // [col][k], stride 72
    __shared__ __align__(16) unsigned short Bs[64 * 72];
    int i0 = PI[blockIdx.x] * 64, j0 = PJ[blockIdx.x] * 64;
    bool diag = (i0 == j0);
    int kb0 = blockIdx.y * KCHUNK2;
    int tid = threadIdx.x;
    int w = tid >> 6, lane = tid & 63;
    int col = lane & 15, quad = lane >> 4;
    floatx4 acc[4] = {};
    for (int step = 0; step < KCHUNK2 / 64; step++) {
        int kb = kb0 + step * 64;
        __syncthreads();
        #pragma unroll
        for (int l = 0; l < 2; l++) {
            int slot = tid + l * 256;
            int row = slot >> 3, grp = slot & 7;
            uint4 da = *(const uint4*)(yT + (size_t)(i0 + row) * KTOT + kb + grp * 8);
            *(uint4*)(&As[row * 72 + grp * 8]) = da;
            if (!diag) {
                uint4 db = *(const uint4*)(yT + (size_t)(j0 + row) * KTOT + kb + grp * 8);
                *(uint4*)(&Bs[row * 72 + grp * 8]) = db;
            }
        }
        __syncthreads();
        const unsigned short* Bb = diag ? As : Bs;
        #pragma unroll
        for (int sub = 0; sub < 2; sub++) {
            short8 a = *(const short8*)(&As[(w * 16 + col) * 72 + sub * 32 + quad * 8]);
            #pragma unroll
            for (int jt = 0; jt < 4; jt++) {
                short8 b = *(const short8*)(&Bb[(jt * 16 + col) * 72 + sub * 32 + quad * 8]);
                acc[jt] = __builtin_amdgcn_mfma_f32_16x16x32_bf16(a, b, acc[jt], 0, 0, 0);
            }
        }
    }
    float* slab = part + ((size_t)blockIdx.y * 10 + blockIdx.x) * 4096;
    #pragma unroll
    for (int jt = 0; jt < 4; jt++)
        #pragma unroll
        for (int r = 0; r < 4; r++)
            slab[(w * 16 + quad * 4 + r) * 64 + jt * 16 + col] = acc[jt][r];
}

// FUSED: block i reduces g row i from the 49 partial slabs (with symmetric
// mirror) into LDS, then computes out row i = lrelu(g_row @ lin_w^T + lin_b).
__global__ __launch_bounds__(256) void greduce_out_kernel(const float* __restrict__ part,
                                                          const float* __restrict__ lin_w,
                                                          const float* __restrict__ lin_b,
                                                          float* __restrict__ out) {
    __shared__ float gs[C];
    int i = blockIdx.x, j = threadIdx.x;
    int a = i >> 6, b = j >> 6;
    int lo = min(a, b), hi = max(a, b);
    int t = lo * (7 - lo) / 2 + hi;          // pair index in PI/PJ order
    int li = (a <= b) ? (i & 63) : (j & 63);
    int lj = (a <= b) ? (j & 63) : (i & 63);
    const float* p = part + (size_t)t * 4096 + li * 64 + lj;
    float s = 0.f;
    for (int z = 0; z < NZB2; z++) s += p[(size_t)z * 40960];
    gs[j] = s;
    __syncthreads();
    float acc = lin_b[j];
    const float* wrow = lin_w + (size_t)j * C;
    for (int k = 0; k < C; k++) acc += gs[k] * wrow[k];
    out[(size_t)i * C + j] = (acc > 0.f) ? acc : SLOPE * acc;
}

extern "C" void kernel_launch(void* const* d_in, const int* in_sizes, int n_in,
                              void* d_out, int out_size, void* d_ws, size_t ws_size,
                              hipStream_t stream) {
    const float* emb    = (const float*)d_in[0];
    const float* conv_w = (const float*)d_in[1];
    const float* conv_b = (const float*)d_in[2];
    const float* lin_w  = (const float*)d_in[3];
    const float* lin_b  = (const float*)d_in[4];
    const int*   eidx   = (const int*)d_in[5];
    const int* node_idx = eidx;        // edge_index[0]
    const int* edge_idx = eidx + NNZ;  // edge_index[1]

    char* ws = (char*)d_ws;
    int* cc_e  = (int*)(ws + OFF_CC_E);
    int* cc_n  = (int*)(ws + OFF_CC_N);
    int* cur_e = (int*)(ws + OFF_CUR_E);
    int* cur_n = (int*)(ws + OFF_CUR_N);
    int* deg_e0 = (int*)(ws + OFF_DEG_E0);
    int* deg_e1 = (int*)(ws + OFF_DEG_E1);
    int* deg_n = (int*)(ws + OFF_DEG_N);
    int* rs_n  = (int*)(ws + OFF_RS_N);
    int* rs_e  = (int*)(ws + OFF_RS_E);
    int* buf_e = (int*)(ws + OFF_BUF_E);
    int* buf_n = (int*)(ws + OFF_BUF_N);
    unsigned short* csr_e = (unsigned short*)(ws + OFF_CSR_E);
    unsigned short* csr_n = (unsigned short*)(ws + OFF_CSR_N);
    uint4* embh4 = (uint4*)(ws + OFF_EMBH);
    unsigned short* e_accp = (unsigned short*)(ws + OFF_EACCP);
    unsigned short* e2h = (unsigned short*)(ws + OFF_E2);
    unsigned short* cwh = (unsigned short*)(ws + OFF_CWH);
    unsigned short* yT  = (unsigned short*)(ws + OFF_YT);
    float* part = (float*)(ws + OFF_PART);
    float* out = (float*)d_out;

    hipMemsetAsync(ws, 0, ZERO_BYTES, stream);   // counters only; graph-capturable

    prep_kernel<<<PREP_EMB_BLOCKS + PREP_CW_BLOCKS + 256, 256, 0, stream>>>(
        (const float4*)emb, embh4, (const float4*)conv_w, (uint4*)cwh,
        node_idx, edge_idx, cc_e, cc_n);

    bucket_scatter_kernel<<<256, 256, 0, stream>>>(node_idx, edge_idx, cc_e, cc_n,
                                                   cur_e, cur_n, buf_e, buf_n);

    bucket_sort_kernel<<<2 * NB, 256, 0, stream>>>(buf_e, buf_n, cc_e, cc_n,
                                                   csr_e, csr_n, rs_e, rs_n,
                                                   deg_e0, deg_e1, deg_n);

    edge_aggregate_kernel<<<8 * EAGG_G, 256, 0, stream>>>(embh4, csr_e, rs_e,
                                                          deg_e0, deg_e1, e_accp);

    edge_gemm_mfma_kernel<<<dim3(MPAD / 64, C / 64), 256, 0, stream>>>(e_accp, cwh,
                                                                       deg_e0, deg_e1, e2h);

    node_aggregate_t_kernel<<<4 * NAGG_G, 256, 0, stream>>>((const uint4*)e2h, csr_n, rs_n,
                                                            deg_n, conv_b, yT);

    gram_mfma_kernel<<<dim3(10, NZB2), 256, 0, stream>>>(yT, part);

    greduce_out_kernel<<<C, 256, 0, stream>>>(part, lin_w, lin_b, out);
}

// Round 15
// 247.920 us; speedup vs baseline: 1.2074x; 1.0071x over previous
//
#include <hip/hip_runtime.h>

#define N_NODES 50000
#define N_EDGES 10000
#define NNZ     800000
#define C       256
#define SLOPE   0.01f
#define KTOT    50176   // node count padded to 512*98
#define KCHUNK2 1024    // gram: 2 x 512 chunks per block
#define NZB2    49      // KTOT / KCHUNK2
#define MPAD    10048   // edge count padded to multiple of 64
#define NHALF   25000   // node-id half boundary (edge-side partitions)

#define NB      250     // coarse buckets per side
#define EB_E    40      // edges per bucket   (250*40  = 10000)
#define EB_N    200     // nodes per bucket   (250*200 = 50000)
#define CHUNK   3125    // NNZ / 256 blocks
#define CAP     6000    // LDS item capacity in bucket_sort (mean 3200, sd ~57)
#define OCAP    5376    // LDS staged-output capacity (ushorts); psz <= ~4800
#define MP_E    576     // per-bucket pad slack, edge side (80 bins * 7 + align 8)
#define MP_N    1408    // per-bucket pad slack, node side (200 rows * 7 + align 8)

#define EAGG_G  314     // edge-agg blocks per partition (314*32 = 10048 = MPAD), 8 parts
#define NAGG_G  1568    // node-agg blocks per slice (1568*32 = 50176 = KTOT), 4 slices

// ---- workspace layout (bytes) ----
#define OFF_CC_E    0          // 250*4 coarse counts (edge)
#define OFF_CC_N    1024       // 250*4 coarse counts (node)
#define OFF_CUR_E   2048       // 250*4 scatter cursors
#define OFF_CUR_N   3072       // 250*4
#define ZERO_BYTES  4096       // zeroed via hipMemsetAsync (counters only)
#define OFF_DEG_E0  4096       // 10048*4 half-0 degrees -> 44288
#define OFF_DEG_E1  45056      // 10048*4 half-1 degrees -> 85248
#define OFF_DEG_N   86016      // 50176*4 node degrees -> 286720
#define OFF_RS_N    290816     // 50001*4 PADDED row starts -> 490820
#define OFF_RS_E    491520     // 10001*4 PADDED row starts (half0 base) -> 531524
#define OFF_BUF_E   532480     // 800000*4 bucketed items (edge side)
#define OFF_BUF_N   3732480    // 800000*4 bucketed items (node side)
#define OFF_CSR_E   6932480    // <=944000*2 ushort node ids, per-HALF 8-padded
#define OFF_CSR_N   8820480    // <=1152000*2 ushort edge ids, rows 8-padded
#define OFF_EMBH    13308672   // SLICE-MAJOR [4][50001][64ch] bf16 (node 50000 zero)
#define OFF_YT      13308672   // 256*50176*2 bf16 — ALIASES embh (embh dead before
                               // node_aggregate writes yT); ends 38,998,784
#define OFF_E2      44144640   // SLICE-MAJOR [4][10048][64ch] bf16; rows >=10000 ZERO
#define OFF_CWH     49289216   // 256*256*2 bf16 conv_w
#define OFF_PART    49420288   // 49*10*4096*4 gram partials -> 57,448,448
#define OFF_EACCP   OFF_PART   // ALIASES part: [2][10048][256] bf16 edge partial sums

typedef __attribute__((ext_vector_type(8))) short short8;
typedef __attribute__((ext_vector_type(4))) float floatx4;

static __device__ __forceinline__ unsigned short f2bf(float f) {
    unsigned int u = __float_as_uint(f);
    u = (u + 0x7fffu + ((u >> 16) & 1u)) >> 16;   // RNE
    return (unsigned short)u;
}

// unpack uint4 (8 bf16) and accumulate into a[0..7]
static __device__ __forceinline__ void acc_bf8(const uint4 d, float* a) {
    a[0] += __uint_as_float(d.x << 16);
    a[1] += __uint_as_float(d.x & 0xffff0000u);
    a[2] += __uint_as_float(d.y << 16);
    a[3] += __uint_as_float(d.y & 0xffff0000u);
    a[4] += __uint_as_float(d.z << 16);
    a[5] += __uint_as_float(d.z & 0xffff0000u);
    a[6] += __uint_as_float(d.w << 16);
    a[7] += __uint_as_float(d.w & 0xffff0000u);
}

// extract 8 ushort indices from one uint4 (16B of csr)
static __device__ __forceinline__ void idx8(const uint4 pk, int* ix) {
    ix[0] = (int)(pk.x & 0xffffu); ix[1] = (int)(pk.x >> 16);
    ix[2] = (int)(pk.y & 0xffffu); ix[3] = (int)(pk.y >> 16);
    ix[4] = (int)(pk.z & 0xffffu); ix[5] = (int)(pk.z >> 16);
    ix[6] = (int)(pk.w & 0xffffu); ix[7] = (int)(pk.w >> 16);
}

// bf16 pairwise add of two packed-bf16 words / uint4s (via f32)
static __device__ __forceinline__ unsigned bfadd2(unsigned x, unsigned y) {
    float lx = __uint_as_float(x << 16), hx = __uint_as_float(x & 0xffff0000u);
    float ly = __uint_as_float(y << 16), hy = __uint_as_float(y & 0xffff0000u);
    return (unsigned)f2bf(lx + ly) | ((unsigned)f2bf(hx + hy) << 16);
}
static __device__ __forceinline__ uint4 bfadd8(uint4 x, uint4 y) {
    x.x = bfadd2(x.x, y.x); x.y = bfadd2(x.y, y.y);
    x.z = bfadd2(x.z, y.z); x.w = bfadd2(x.w, y.w);
    return x;
}

// FUSED prep: blocks [0,6251) cast emb->bf16 SLICE-MAJOR [4][50001][64ch],
// [6251,6283) cast conv_w->bf16, [6283,6539) coarse histogram.
#define PREP_EMB_BLOCKS 6251
#define PREP_CW_BLOCKS  32
__global__ __launch_bounds__(256) void prep_kernel(const float4* __restrict__ emb4,
                                                   uint4* __restrict__ embh4,
                                                   const float4* __restrict__ cw4,
                                                   uint4* __restrict__ cwh4,
                                                   const int* __restrict__ node_idx,
                                                   const int* __restrict__ edge_idx,
                                                   int* __restrict__ cc_e,
                                                   int* __restrict__ cc_n) {
    __shared__ int he[NB], hn[NB];
    int b = blockIdx.x, tid = threadIdx.x;
    if (b < PREP_EMB_BLOCKS) {
        int i = b * 256 + tid;
        if (i >= 1600032) return;
        uint4 o = {0u, 0u, 0u, 0u};
        if (i < 1600000) {
            float4 f0 = emb4[2 * i], f1 = emb4[2 * i + 1];
            o.x = f2bf(f0.x) | ((unsigned)f2bf(f0.y) << 16);
            o.y = f2bf(f0.z) | ((unsigned)f2bf(f0.w) << 16);
            o.z = f2bf(f1.x) | ((unsigned)f2bf(f1.y) << 16);
            o.w = f2bf(f1.z) | ((unsigned)f2bf(f1.w) << 16);
        }
        // slice-major 64ch: node = i>>5, chunk c = i&31 (8 ch each),
        // slice = c>>3 (4 slices of 8 uint4), pos = c&7
        int node = i >> 5, c = i & 31;
        embh4[((size_t)(c >> 3) * 50001 + node) * 8 + (c & 7)] = o;
    } else if (b < PREP_EMB_BLOCKS + PREP_CW_BLOCKS) {
        int i = (b - PREP_EMB_BLOCKS) * 256 + tid;   // < 8192
        float4 f0 = cw4[2 * i], f1 = cw4[2 * i + 1];
        uint4 o;
        o.x = f2bf(f0.x) | ((unsigned)f2bf(f0.y) << 16);
        o.y = f2bf(f0.z) | ((unsigned)f2bf(f0.w) << 16);
        o.z = f2bf(f1.x) | ((unsigned)f2bf(f1.y) << 16);
        o.w = f2bf(f1.z) | ((unsigned)f2bf(f1.w) << 16);
        cwh4[i] = o;
    } else {
        int base = (b - PREP_EMB_BLOCKS - PREP_CW_BLOCKS) * CHUNK;
        for (int i = tid; i < NB; i += 256) { he[i] = 0; hn[i] = 0; }
        __syncthreads();
        for (int i = tid; i < CHUNK; i += 256) {
            atomicAdd(&he[edge_idx[base + i] / EB_E], 1);
            atomicAdd(&hn[node_idx[base + i] / EB_N], 1);
        }
        __syncthreads();
        for (int k = tid; k < NB; k += 256) {
            if (he[k]) atomicAdd(&cc_e[k], he[k]);
            if (hn[k]) atomicAdd(&cc_n[k], hn[k]);
        }
    }
}

// pass 1: scatter into coarse buckets. Coarse bases computed IN-BLOCK via a
// 250-element LDS scan of cc. Items carried in REGISTERS between phases
// ((v<<14)|e pack — no re-read of idx arrays in the write phase).
__global__ __launch_bounds__(256) void bucket_scatter_kernel(const int* __restrict__ node_idx,
                                                             const int* __restrict__ edge_idx,
                                                             const int* __restrict__ cc_e,
                                                             const int* __restrict__ cc_n,
                                                             int* __restrict__ cur_e,
                                                             int* __restrict__ cur_n,
                                                             int* __restrict__ buf_e,
                                                             int* __restrict__ buf_n) {
    __shared__ int he[NB], hn[NB], be[NB], bn[NB];
    __shared__ int cbl_e[NB], cbl_n[NB], tmp[256];
    int tid = threadIdx.x;
    int base = blockIdx.x * CHUNK;
    // exclusive scans of cc_e / cc_n
    int v = (tid < NB) ? cc_e[tid] : 0;
    tmp[tid] = v;
    __syncthreads();
    for (int off = 1; off < 256; off <<= 1) {
        int t = (tid >= off) ? tmp[tid - off] : 0;
        __syncthreads();
        tmp[tid] += t;
        __syncthreads();
    }
    if (tid < NB) cbl_e[tid] = tmp[tid] - v;
    __syncthreads();
    v = (tid < NB) ? cc_n[tid] : 0;
    tmp[tid] = v;
    __syncthreads();
    for (int off = 1; off < 256; off <<= 1) {
        int t = (tid >= off) ? tmp[tid - off] : 0;
        __syncthreads();
        tmp[tid] += t;
        __syncthreads();
    }
    if (tid < NB) cbl_n[tid] = tmp[tid] - v;
    for (int i = tid; i < NB; i += 256) { he[i] = 0; hn[i] = 0; }
    __syncthreads();
    int pe[13], pn[13];   // (bucket<<12) | local_offset ; offset < 3125 < 4096
    int ev[13];           // (v<<14) | e  (v<50000 fits 16b, e<10000 fits 14b)
    #pragma unroll
    for (int k = 0; k < 13; k++) {
        int i = tid + k * 256;
        if (i < CHUNK) {
            int e = edge_idx[base + i], v2 = node_idx[base + i];
            ev[k] = (v2 << 14) | e;
            int ke = e / EB_E, kn = v2 / EB_N;
            pe[k] = (ke << 12) | atomicAdd(&he[ke], 1);
            pn[k] = (kn << 12) | atomicAdd(&hn[kn], 1);
        }
    }
    __syncthreads();
    for (int k = tid; k < NB; k += 256) {
        int c = he[k];
        be[k] = cbl_e[k] + (c ? atomicAdd(&cur_e[k], c) : 0);
        int cn = hn[k];
        bn[k] = cbl_n[k] + (cn ? atomicAdd(&cur_n[k], cn) : 0);
    }
    __syncthreads();
    #pragma unroll
    for (int k = 0; k < 13; k++) {
        int i = tid + k * 256;
        if (i < CHUNK) {
            int e = ev[k] & 16383, v2 = ev[k] >> 14;
            int ke = pe[k] >> 12, oe = pe[k] & 4095;
            buf_e[be[ke] + oe] = (v2 << 7) | ((e - ke * EB_E) * 2 + (v2 >= NHALF ? 1 : 0));
            int kn = pn[k] >> 12, on = pn[k] & 4095;
            buf_n[bn[kn] + on] = (e << 8) | (v2 - kn * EB_N);
        }
    }
}

// pass 2: per-bucket LDS counting sort -> PADDED CSR. Edge side: 80 bins
// (row, half); node side: 200 rows 8-padded. Output is STAGED in LDS and
// streamed out as coalesced 16B stores (guarded fallback to direct writes).
// Coarse base recomputed in-block via LDS scan of cc.
__global__ __launch_bounds__(256) void bucket_sort_kernel(const int* __restrict__ buf_e,
                                                          const int* __restrict__ buf_n,
                                                          const int* __restrict__ cc_e,
                                                          const int* __restrict__ cc_n,
                                                          unsigned short* __restrict__ csr_e,
                                                          unsigned short* __restrict__ csr_n,
                                                          int* __restrict__ rs_e,
                                                          int* __restrict__ rs_n,
                                                          int* __restrict__ deg_e0,
                                                          int* __restrict__ deg_e1,
                                                          int* __restrict__ deg_n) {
    __shared__ int A[CAP];
    __shared__ unsigned short O[OCAP];
    __shared__ int h[EB_N], bs[EB_N], cs[EB_N];
    __shared__ int tmp[256];
    int tid = threadIdx.x;
    bool edgeSide = blockIdx.x < NB;
    int k = edgeSide ? blockIdx.x : blockIdx.x - NB;
    int rows = edgeSide ? EB_E : EB_N;
    int bins = edgeSide ? 2 * EB_E : EB_N;
    int shift = edgeSide ? 7 : 8;
    int mask = (1 << shift) - 1;
    int mp = edgeSide ? MP_E : MP_N;
    int sent = edgeSide ? N_NODES : N_EDGES;
    const int* cc  = edgeSide ? cc_e : cc_n;
    const int* buf = edgeSide ? buf_e : buf_n;
    unsigned short* csr = edgeSide ? csr_e : csr_n;
    int* rs  = edgeSide ? rs_e : rs_n;
    // in-block exclusive scan of cc -> this bucket's exact base
    int vv = (tid < NB) ? cc[tid] : 0;
    tmp[tid] = vv;
    __syncthreads();
    for (int off = 1; off < 256; off <<= 1) {
        int t = (tid >= off) ? tmp[tid - off] : 0;
        __syncthreads();
        tmp[tid] += t;
        __syncthreads();
    }
    __shared__ int baseSh;
    if (tid == k) baseSh = tmp[k] - vv;
    __syncthreads();
    int base = baseSh;                              // exact base (buf reads)
    int base_pad = (base + k * mp + 7) & ~7;        // 8-aligned padded base (csr writes)
    int cnt = cc[k];
    for (int i = tid; i < bins; i += 256) h[i] = 0;
    __syncthreads();
    for (int i = tid; i < cnt; i += 256) {
        int it = buf[base + i];
        if (i < CAP) A[i] = it;
        atomicAdd(&h[it & mask], 1);
    }
    __syncthreads();
    if (tid == 0) {
        int s = 0;
        for (int j = 0; j < bins; j++) { bs[j] = s; s += (h[j] + 7) & ~7; }
    }
    __syncthreads();
    for (int j = tid; j < bins; j += 256) { cs[j] = h[j]; h[j] = 0; }
    __syncthreads();
    for (int j = tid; j < rows; j += 256) {
        if (edgeSide) {
            rs[k * EB_E + j] = base_pad + bs[2 * j];
            deg_e0[k * EB_E + j] = cs[2 * j];
            deg_e1[k * EB_E + j] = cs[2 * j + 1];
        } else {
            rs[k * EB_N + j] = base_pad + bs[j];
            deg_n[k * EB_N + j] = cs[j];
        }
    }
    if (k == NB - 1) {
        if (tid == 0) rs[edgeSide ? N_EDGES : N_NODES] = NNZ;
        if (edgeSide) {
            if (tid < MPAD - N_EDGES) { deg_e0[N_EDGES + tid] = 0; deg_e1[N_EDGES + tid] = 0; }
        } else {
            for (int x = tid; x < KTOT - N_NODES; x += 256) deg_n[N_NODES + x] = 0;
        }
    }
    __syncthreads();
    int psz = bs[bins - 1] + ((cs[bins - 1] + 7) & ~7);   // padded total size
    if (psz <= OCAP) {
        // staged path: sort into LDS, stream out coalesced 16B stores
        for (int s = tid; s < psz; s += 256) O[s] = (unsigned short)sent;
        __syncthreads();
        for (int i = tid; i < cnt; i += 256) {
            int it = (i < CAP) ? A[i] : buf[base + i];
            int loc = it & mask;
            int off = bs[loc] + atomicAdd(&h[loc], 1);
            O[off] = (unsigned short)(it >> shift);
        }
        __syncthreads();
        uint4* dst = (uint4*)(csr + base_pad);
        const uint4* src = (const uint4*)O;
        for (int s = tid; s * 8 < psz; s += 256) dst[s] = src[s];
    } else {
        // fallback: direct scattered writes
        for (int j = tid; j < bins; j += 256) {
            int c0 = cs[j], e0 = (c0 + 7) & ~7;
            for (int x = c0; x < e0; x++) csr[base_pad + bs[j] + x] = (unsigned short)sent;
        }
        for (int i = tid; i < cnt; i += 256) {
            int it = (i < CAP) ? A[i] : buf[base + i];
            int loc = it & mask;
            int off = bs[loc] + atomicAdd(&h[loc], 1);
            csr[base_pad + off] = (unsigned short)(it >> shift);
        }
    }
}

// Edge aggregation, 8 partitions = 4 ch-slices x 2 node-halves (3.2MB each,
// one per XCD). Each 8-lane group owns an edge and scans ONLY its half's
// pre-sorted sub-range: unconditional 128B gathers, zero masked waste, no
// cross-lane reduction. Writes bf16 PARTIAL sums e_accP[half][MPAD][256].
__global__ __launch_bounds__(256) void edge_aggregate_kernel(const uint4* __restrict__ embh4,
                                                             const unsigned short* __restrict__ csr_e,
                                                             const int* __restrict__ rs_e,
                                                             const int* __restrict__ deg_e0,
                                                             const int* __restrict__ deg_e1,
                                                             unsigned short* __restrict__ e_accp) {
    int sid = blockIdx.x & 7, g = blockIdx.x >> 3;  // g in [0, 314)
    int cslice = sid & 3, half = sid >> 2;
    const uint4* __restrict__ csr4 = (const uint4*)csr_e;
    int tid = threadIdx.x;
    int group = tid >> 3, l8 = tid & 7;
    const uint4* __restrict__ tbl = embh4 + (size_t)cslice * 50001 * 8 + l8;
    int e = g * 32 + group;                         // < MPAD (314*32 = 10048)
    int s = rs_e[min(e, N_EDGES)];
    int d0 = deg_e0[e], d1 = deg_e1[e];             // pad rows: 0 -> loop skipped
    int start = half ? s + ((d0 + 7) & ~7) : s;
    int dgh = half ? d1 : d0;
    int c0 = start >> 3, nc = (dgh + 7) >> 3;
    float a[8] = {0.f, 0.f, 0.f, 0.f, 0.f, 0.f, 0.f, 0.f};
    for (int c = c0; c < c0 + nc; c++) {
        uint4 pk = csr4[c];                         // broadcast across the 8 lanes
        int ix[8];
        idx8(pk, ix);
        #pragma unroll
        for (int j = 0; j < 8; j++) acc_bf8(tbl[(size_t)ix[j] * 8], a);
    }
    uint4 o;
    o.x = f2bf(a[0]) | ((unsigned)f2bf(a[1]) << 16);
    o.y = f2bf(a[2]) | ((unsigned)f2bf(a[3]) << 16);
    o.z = f2bf(a[4]) | ((unsigned)f2bf(a[5]) << 16);
    o.w = f2bf(a[6]) | ((unsigned)f2bf(a[7]) << 16);
    *(uint4*)(e_accp + ((size_t)half * MPAD + e) * C + cslice * 64 + l8 * 8) = o;
}

// e2[m][n] = Binv[m] * sum_k (e_accP0+e_accP1)[m][k] * conv_w[n][k] via MFMA;
// grid (157,4); output SLICE-MAJOR [4][MPAD][64ch]; pad rows ZERO.
__global__ __launch_bounds__(256) void edge_gemm_mfma_kernel(const unsigned short* __restrict__ e_accp,
                                                             const unsigned short* __restrict__ cwh,
                                                             const int* __restrict__ deg_e0,
                                                             const int* __restrict__ deg_e1,
                                                             unsigned short* __restrict__ e2h) {
    __shared__ __align__(16) unsigned short As[64 * 72];
    __shared__ __align__(16) unsigned short Bs[64 * 72];
    int i0 = blockIdx.x * 64, j0 = blockIdx.y * 64;
    int tid = threadIdx.x;
    int w = tid >> 6, lane = tid & 63;
    int col = lane & 15, quad = lane >> 4;
    floatx4 acc[4] = {};
    for (int step = 0; step < 4; step++) {
        int kb = step * 64;
        __syncthreads();
        #pragma unroll
        for (int l = 0; l < 2; l++) {
            int slot = tid + l * 256;
            int row = slot >> 3, grp = slot & 7;
            uint4 d0 = *(const uint4*)(e_accp + (size_t)(i0 + row) * C + kb + grp * 8);
            uint4 d1 = *(const uint4*)(e_accp + ((size_t)MPAD + i0 + row) * C + kb + grp * 8);
            *(uint4*)(&As[row * 72 + grp * 8]) = bfadd8(d0, d1);   // combine halves
            uint4 db = *(const uint4*)(cwh + (size_t)(j0 + row) * C + kb + grp * 8);
            *(uint4*)(&Bs[row * 72 + grp * 8]) = db;
        }
        __syncthreads();
        #pragma unroll
        for (int sub = 0; sub < 2; sub++) {
            short8 a = *(const short8*)(&As[(w * 16 + col) * 72 + sub * 32 + quad * 8]);
            #pragma unroll
            for (int jt = 0; jt < 4; jt++) {
                short8 b = *(const short8*)(&Bs[(jt * 16 + col) * 72 + sub * 32 + quad * 8]);
                acc[jt] = __builtin_amdgcn_mfma_f32_16x16x32_bf16(a, b, acc[jt], 0, 0, 0);
            }
        }
    }
    #pragma unroll
    for (int r = 0; r < 4; r++) {
        int m = i0 + w * 16 + quad * 4 + r;          // < MPAD always
        int dg = deg_e0[m] + deg_e1[m];              // pad rows: 0
        float binv = (dg > 0) ? 1.0f / (float)dg : 0.0f;
        #pragma unroll
        for (int jt = 0; jt < 4; jt++) {
            int ch = j0 + jt * 16 + col;
            e2h[(size_t)((ch >> 6) * MPAD + m) * 64 + (ch & 63)] = f2bf(acc[jt][r] * binv);
        }
    }
}

// XCD-sliced node aggregation, 64-CHANNEL slices (4 slices, table 1.28MB,
// L2-resident): each 8-lane group owns a node; lanes cover one contiguous
// 128B row. Broadcast csr chunk; unconditional unpack (rows 8-padded).
// Fused Dinv/bias/lrelu; LDS transpose; 16B yT stores.
__global__ __launch_bounds__(256) void node_aggregate_t_kernel(const uint4* __restrict__ e2h4,
                                                               const unsigned short* __restrict__ csr_n,
                                                               const int* __restrict__ rs_n,
                                                               const int* __restrict__ deg_n,
                                                               const float* __restrict__ conv_b,
                                                               unsigned short* __restrict__ yT) {
    __shared__ unsigned short T[64][33];   // [slice-ch][node-local], stride 33
    int sid = blockIdx.x & 3, g = blockIdx.x >> 2;
    const uint4* __restrict__ csr4 = (const uint4*)csr_n;
    int tid = threadIdx.x;
    int group = tid >> 3, l8 = tid & 7;
    const uint4* __restrict__ tbl = e2h4 + (size_t)sid * MPAD * 8 + l8;
    int n = g * 32 + group;                         // < KTOT (1568*32 = 50176)
    int s = rs_n[min(n, N_NODES)];
    int dg = deg_n[n];
    int c0 = s >> 3, nc = (dg + 7) >> 3;
    float4 b0 = ((const float4*)conv_b)[sid * 16 + l8 * 2];
    float4 b1 = ((const float4*)conv_b)[sid * 16 + l8 * 2 + 1];
    float a[8] = {0.f, 0.f, 0.f, 0.f, 0.f, 0.f, 0.f, 0.f};
    for (int c = c0; c < c0 + nc; c++) {
        uint4 pk = csr4[c];                         // broadcast across the 8 lanes
        int ix[8];
        idx8(pk, ix);
        #pragma unroll
        for (int j = 0; j < 8; j++) acc_bf8(tbl[(size_t)ix[j] * 8], a);
    }
    float dinv = (dg > 0) ? 1.0f / (float)dg : 0.0f;
    float bb[8] = {b0.x, b0.y, b0.z, b0.w, b1.x, b1.y, b1.z, b1.w};
    #pragma unroll
    for (int jj = 0; jj < 8; jj++) {
        float r = a[jj] * dinv + bb[jj];
        r = (r > 0.f) ? r : SLOPE * r;
        if (n >= N_NODES) r = 0.f;                 // zero-pad rows for gram
        T[l8 * 8 + jj][group] = f2bf(r);
    }
    __syncthreads();
    int rr = tid >> 2, cc = tid & 3;               // 64 rows x 4 packers
    uint4 o;
    o.x = T[rr][cc * 8 + 0] | ((unsigned)T[rr][cc * 8 + 1] << 16);
    o.y = T[rr][cc * 8 + 2] | ((unsigned)T[rr][cc * 8 + 3] << 16);
    o.z = T[rr][cc * 8 + 4] | ((unsigned)T[rr][cc * 8 + 5] << 16);
    o.w = T[rr][cc * 8 + 6] | ((unsigned)T[rr][cc * 8 + 7] << 16);
    *(uint4*)(yT + (size_t)(sid * 64 + rr) * KTOT + g * 32 + cc * 8) = o;
}

// Gram partials via MFMA, symmetry-aware (10 upper-tri tile pairs), NO atomics.
// 1-D grid of 490 with BIJECTIVE XCD swizzle (m204): consecutive wgid -> same
// XCD; pair = wgid%10 fastest, so the 10 pairs sharing a K-band co-locate on
// one XCD and their 512KB tile set is fetched once per XCD.
__global__ __launch_bounds__(256) void gram_mfma_kernel(const unsigned short* __restrict__ yT,
                                                        float* __restrict__ part) {
    static const int PI[10] = {0, 0, 0, 0, 1, 1, 1, 2, 2, 3};
    static const int PJ[10] = {0, 1, 2, 3, 1, 2, 3, 2, 3, 3};
    __shared__ __align__(16) unsigned short As[64 * 72];  // [col][k], stride 72
    __shared__ __align__(16) unsigned short Bs[64 * 72];
    // bijective swizzle, nwg=490: q=61, r=2
    int bid = blockIdx.x;
    int xcd = bid & 7, sub = bid >> 3;
    int wgid = (xcd < 2 ? xcd * 62 : 124 + (xcd - 2) * 61) + sub;
    int pr = wgid % 10, yb = wgid / 10;
    int i0 = PI[pr] * 64, j0 = PJ[pr] * 64;
    bool diag = (i0 == j0);
    int kb0 = yb * KCHUNK2;
    int tid = threadIdx.x;
    int w = tid >> 6, lane = tid & 63;
    int col = lane & 15, quad = lane >> 4;
    floatx4 acc[4] = {};
    for (int step = 0; step < KCHUNK2 / 64; step++) {
        int kb = kb0 + step * 64;
        __syncthreads();
        #pragma unroll
        for (int l = 0; l < 2; l++) {
            int slot = tid + l * 256;
            int row = slot >> 3, grp = slot & 7;
            uint4 da = *(const uint4*)(yT + (size_t)(i0 + row) * KTOT + kb + grp * 8);
            *(uint4*)(&As[row * 72 + grp * 8]) = da;
            if (!diag) {
                uint4 db = *(const uint4*)(yT + (size_t)(j0 + row) * KTOT + kb + grp * 8);
                *(uint4*)(&Bs[row * 72 + grp * 8]) = db;
            }
        }
        __syncthreads();
        const unsigned short* Bb = diag ? As : Bs;
        #pragma unroll
        for (int sub2 = 0; sub2 < 2; sub2++) {
            short8 a = *(const short8*)(&As[(w * 16 + col) * 72 + sub2 * 32 + quad * 8]);
            #pragma unroll
            for (int jt = 0; jt < 4; jt++) {
                short8 b = *(const short8*)(&Bb[(jt * 16 + col) * 72 + sub2 * 32 + quad * 8]);
                acc[jt] = __builtin_amdgcn_mfma_f32_16x16x32_bf16(a, b, acc[jt], 0, 0, 0);
            }
        }
    }
    float* slab = part + ((size_t)yb * 10 + pr) * 4096;
    #pragma unroll
    for (int jt = 0; jt < 4; jt++)
        #pragma unroll
        for (int r = 0; r < 4; r++)
            slab[(w * 16 + quad * 4 + r) * 64 + jt * 16 + col] = acc[jt][r];
}

// FUSED: block i reduces g row i from the 49 partial slabs (with symmetric
// mirror) into LDS, then computes out row i = lrelu(g_row @ lin_w^T + lin_b).
__global__ __launch_bounds__(256) void greduce_out_kernel(const float* __restrict__ part,
                                                          const float* __restrict__ lin_w,
                                                          const float* __restrict__ lin_b,
                                                          float* __restrict__ out) {
    __shared__ float gs[C];
    int i = blockIdx.x, j = threadIdx.x;
    int a = i >> 6, b = j >> 6;
    int lo = min(a, b), hi = max(a, b);
    int t = lo * (7 - lo) / 2 + hi;          // pair index in PI/PJ order
    int li = (a <= b) ? (i & 63) : (j & 63);
    int lj = (a <= b) ? (j & 63) : (i & 63);
    const float* p = part + (size_t)t * 4096 + li * 64 + lj;
    float s = 0.f;
    for (int z = 0; z < NZB2; z++) s += p[(size_t)z * 40960];
    gs[j] = s;
    __syncthreads();
    float acc = lin_b[j];
    const float* wrow = lin_w + (size_t)j * C;
    for (int k = 0; k < C; k++) acc += gs[k] * wrow[k];
    out[(size_t)i * C + j] = (acc > 0.f) ? acc : SLOPE * acc;
}

extern "C" void kernel_launch(void* const* d_in, const int* in_sizes, int n_in,
                              void* d_out, int out_size, void* d_ws, size_t ws_size,
                              hipStream_t stream) {
    const float* emb    = (const float*)d_in[0];
    const float* conv_w = (const float*)d_in[1];
    const float* conv_b = (const float*)d_in[2];
    const float* lin_w  = (const float*)d_in[3];
    const float* lin_b  = (const float*)d_in[4];
    const int*   eidx   = (const int*)d_in[5];
    const int* node_idx = eidx;        // edge_index[0]
    const int* edge_idx = eidx + NNZ;  // edge_index[1]

    char* ws = (char*)d_ws;
    int* cc_e  = (int*)(ws + OFF_CC_E);
    int* cc_n  = (int*)(ws + OFF_CC_N);
    int* cur_e = (int*)(ws + OFF_CUR_E);
    int* cur_n = (int*)(ws + OFF_CUR_N);
    int* deg_e0 = (int*)(ws + OFF_DEG_E0);
    int* deg_e1 = (int*)(ws + OFF_DEG_E1);
    int* deg_n = (int*)(ws + OFF_DEG_N);
    int* rs_n  = (int*)(ws + OFF_RS_N);
    int* rs_e  = (int*)(ws + OFF_RS_E);
    int* buf_e = (int*)(ws + OFF_BUF_E);
    int* buf_n = (int*)(ws + OFF_BUF_N);
    unsigned short* csr_e = (unsigned short*)(ws + OFF_CSR_E);
    unsigned short* csr_n = (unsigned short*)(ws + OFF_CSR_N);
    uint4* embh4 = (uint4*)(ws + OFF_EMBH);
    unsigned short* e_accp = (unsigned short*)(ws + OFF_EACCP);
    unsigned short* e2h = (unsigned short*)(ws + OFF_E2);
    unsigned short* cwh = (unsigned short*)(ws + OFF_CWH);
    unsigned short* yT  = (unsigned short*)(ws + OFF_YT);
    float* part = (float*)(ws + OFF_PART);
    float* out = (float*)d_out;

    hipMemsetAsync(ws, 0, ZERO_BYTES, stream);   // counters only; graph-capturable

    prep_kernel<<<PREP_EMB_BLOCKS + PREP_CW_BLOCKS + 256, 256, 0, stream>>>(
        (const float4*)emb, embh4, (const float4*)conv_w, (uint4*)cwh,
        node_idx, edge_idx, cc_e, cc_n);

    bucket_scatter_kernel<<<256, 256, 0, stream>>>(node_idx, edge_idx, cc_e, cc_n,
                                                   cur_e, cur_n, buf_e, buf_n);

    bucket_sort_kernel<<<2 * NB, 256, 0, stream>>>(buf_e, buf_n, cc_e, cc_n,
                                                   csr_e, csr_n, rs_e, rs_n,
                                                   deg_e0, deg_e1, deg_n);

    edge_aggregate_kernel<<<8 * EAGG_G, 256, 0, stream>>>(embh4, csr_e, rs_e,
                                                          deg_e0, deg_e1, e_accp);

    edge_gemm_mfma_kernel<<<dim3(MPAD / 64, C / 64), 256, 0, stream>>>(e_accp, cwh,
                                                                       deg_e0, deg_e1, e2h);

    node_aggregate_t_kernel<<<4 * NAGG_G, 256, 0, stream>>>((const uint4*)e2h, csr_n, rs_n,
                                                            deg_n, conv_b, yT);

    gram_mfma_kernel<<<10 * NZB2, 256, 0, stream>>>(yT, part);

    greduce_out_kernel<<<C, 256, 0, stream>>>(part, lin_w, lin_b, out);
}